// Round 1
// baseline (9713.565 us; speedup 1.0000x reference)
//
#include <hip/hip_runtime.h>
#include <hip/hip_bf16.h>
#include <math.h>

// ---------- dims ----------
#define BATCH 17          // search + 16 exemplars
#define T_EX 16
#define H0 383
#define W0 287
#define C1 64
#define H1 95
#define W1 71
#define H1P 47
#define W1P 35
#define C2 192
#define H2P 23
#define W2P 17
#define C3 384
#define C45 256
#define H5P 11
#define W5P 8
#define DD 256
#define MM 88            // 11*8
#define TM 1408          // 16*88

__device__ __forceinline__ float lrelu(float v) { return v > 0.f ? v : 0.01f * v; }

// ---------- conv1: 3->64, k11, s4, p2, fused relu ----------
__global__ void conv1_k(const float* __restrict__ search, const float* __restrict__ exemp,
                        const float* __restrict__ w, const float* __restrict__ bias,
                        float* __restrict__ out) {
    const int HW = H1 * W1;      // 6745
    const int tiles = (HW + 255) / 256; // 27
    int bid = blockIdx.x;
    int tile = bid % tiles;
    int oc = (bid / tiles) % C1;
    int b = bid / (tiles * C1);
    __shared__ float lw[3 * 11 * 11];
    for (int j = threadIdx.x; j < 363; j += 256) lw[j] = w[oc * 363 + j];
    __syncthreads();
    int p = tile * 256 + threadIdx.x;
    if (p >= HW) return;
    int y = p / W1, x = p % W1;
    const float* inb = (b == 0) ? search : (exemp + (size_t)(b - 1) * 3 * H0 * W0);
    float acc = bias[oc];
    for (int i = 0; i < 3; ++i) {
        const float* inc = inb + i * H0 * W0;
        const float* lwi = lw + i * 121;
        for (int ky = 0; ky < 11; ++ky) {
            int iy = 4 * y - 2 + ky;
            if (iy < 0 || iy >= H0) continue;
            const float* row = inc + iy * W0;
            for (int kx = 0; kx < 11; ++kx) {
                int ix = 4 * x - 2 + kx;
                if (ix < 0 || ix >= W0) continue;
                acc = fmaf(lwi[ky * 11 + kx], row[ix], acc);
            }
        }
    }
    out[((size_t)(b * C1 + oc)) * HW + p] = fmaxf(acc, 0.f);
}

// ---------- generic same-pad conv with fused relu (k3p1 / k5p2) ----------
template <int CIN, int K, int PAD>
__global__ void convk(const float* __restrict__ in, const float* __restrict__ w,
                      const float* __restrict__ bias, float* __restrict__ out,
                      int Cout, int H, int W) {
    int HW = H * W;
    int tiles = (HW + 255) >> 8;
    int bid = blockIdx.x;
    int tile = bid % tiles;
    int oc = (bid / tiles) % Cout;
    int b = bid / (tiles * Cout);
    extern __shared__ float lw[];
    const int WSZ = CIN * K * K;
    for (int j = threadIdx.x; j < WSZ; j += 256) lw[j] = w[oc * WSZ + j];
    __syncthreads();
    int p = tile * 256 + threadIdx.x;
    if (p >= HW) return;
    int y = p / W, x = p % W;
    const float* inb = in + (size_t)b * CIN * HW;
    float acc = bias[oc];
    for (int i = 0; i < CIN; ++i) {
        const float* inc = inb + i * HW;
        const float* lwi = lw + i * K * K;
#pragma unroll
        for (int ky = 0; ky < K; ++ky) {
            int iy = y - PAD + ky;
            if (iy < 0 || iy >= H) continue;
            const float* row = inc + iy * W;
#pragma unroll
            for (int kx = 0; kx < K; ++kx) {
                int ix = x - PAD + kx;
                if (ix < 0 || ix >= W) continue;
                acc = fmaf(lwi[ky * K + kx], row[ix], acc);
            }
        }
    }
    out[((size_t)(b * Cout + oc)) * HW + p] = fmaxf(acc, 0.f);
}

// ---------- maxpool k3 s2 VALID ----------
__global__ void maxpool_k(const float* __restrict__ in, float* __restrict__ out,
                          int C, int Hin, int Win, int Hout, int Wout) {
    int total = BATCH * C * Hout * Wout;
    int idx = blockIdx.x * 256 + threadIdx.x;
    if (idx >= total) return;
    int x = idx % Wout; int t = idx / Wout;
    int y = t % Hout; t /= Hout;
    int c = t % C; int b = t / C;
    const float* p = in + ((size_t)(b * C + c) * Hin + 2 * y) * Win + 2 * x;
    float m = p[0];
    m = fmaxf(m, p[1]); m = fmaxf(m, p[2]);
    m = fmaxf(m, p[Win]); m = fmaxf(m, p[Win + 1]); m = fmaxf(m, p[Win + 2]);
    m = fmaxf(m, p[2 * Win]); m = fmaxf(m, p[2 * Win + 1]); m = fmaxf(m, p[2 * Win + 2]);
    out[idx] = m;
}

// ---------- conv_deconv: conv1d(k3,p1) + global max over positions -> v[256] ----------
__global__ void cdv_k(const float* __restrict__ Xf, const float* __restrict__ wcd,
                      const float* __restrict__ bcd, float* __restrict__ v) {
    int c = blockIdx.x;       // 256
    int m = threadIdx.x;      // 128 threads
    float val = -INFINITY;
    if (m < MM) {
        float acc = bcd[c];
        const float* wrow = wcd + c * 256 * 3;
        for (int i = 0; i < 256; ++i) {
            const float* xr = Xf + i * MM;
            float w0 = wrow[i * 3 + 0], w1 = wrow[i * 3 + 1], w2 = wrow[i * 3 + 2];
            if (m > 0) acc = fmaf(w0, xr[m - 1], acc);
            acc = fmaf(w1, xr[m], acc);
            if (m < MM - 1) acc = fmaf(w2, xr[m + 1], acc);
        }
        val = acc;
    }
    __shared__ float red[128];
    red[threadIdx.x] = val;
    __syncthreads();
    for (int s = 64; s > 0; s >>= 1) {
        if (threadIdx.x < s) red[threadIdx.x] = fmaxf(red[threadIdx.x], red[threadIdx.x + s]);
        __syncthreads();
    }
    if (threadIdx.x == 0) v[c] = red[0];
}

// ---------- X_hat[o,k] = sum_i v[i]*wt[i,o,k] + bt[o] ----------
__global__ void xhat_k(const float* __restrict__ v, const float* __restrict__ wt,
                       const float* __restrict__ bt, float* __restrict__ xhat) {
    __shared__ float lv[256];
    for (int j = threadIdx.x; j < 256; j += 256) lv[j] = v[j];
    __syncthreads();
    int idx = blockIdx.x * 256 + threadIdx.x;
    if (idx >= DD * MM) return;
    int k = idx % MM, o = idx / MM;
    float acc = bt[o];
    for (int i = 0; i < 256; ++i) acc = fmaf(lv[i], wt[(i * 256 + o) * MM + k], acc);
    xhat[idx] = acc;
}

// ---------- Y1 = nodes @ ws1 : [1408,512]; nodes[n=m*16+t][d] = P[(1+t)*22528 + d*88 + m] ----------
__global__ void y1_k(const float* __restrict__ P, const float* __restrict__ ws1,
                     float* __restrict__ Y1) {
    int idx = blockIdx.x * 256 + threadIdx.x;
    if (idx >= TM * 512) return;
    int c = idx % 512; int n = idx / 512;
    int t = n % T_EX, m = n / T_EX;
    const float* node = P + (size_t)(1 + t) * (DD * MM) + m;
    float acc = 0.f;
    for (int d = 0; d < 256; ++d) acc = fmaf(node[d * MM], ws1[d * 512 + c], acc);
    Y1[idx] = acc;
}

// ---------- S1[t][c] = sum_m Y1[(m*16+t)*512+c] ----------
__global__ void s1_k(const float* __restrict__ Y1, float* __restrict__ S1) {
    int idx = blockIdx.x * 256 + threadIdx.x;
    if (idx >= T_EX * 512) return;
    int c = idx % 512, t = idx / 512;
    float acc = 0.f;
    for (int m = 0; m < MM; ++m) acc += Y1[(m * T_EX + t) * 512 + c];
    S1[idx] = acc;
}

// ---------- h1 = lrelu(S_t - (t==0)*Y1 + bs1) ----------
__global__ void h1_k(const float* __restrict__ Y1, const float* __restrict__ S1,
                     const float* __restrict__ bs1, float* __restrict__ h1) {
    int idx = blockIdx.x * 256 + threadIdx.x;
    if (idx >= TM * 512) return;
    int c = idx % 512; int n = idx / 512;
    int t = n % T_EX;
    float val = S1[t * 512 + c] + bs1[c];
    if (t == 0) val -= Y1[idx];
    h1[idx] = lrelu(val);
}

// ---------- Y2 = h1 @ ws2 : [1408,256] ----------
__global__ void y2_k(const float* __restrict__ h1, const float* __restrict__ ws2,
                     float* __restrict__ Y2) {
    int idx = blockIdx.x * 256 + threadIdx.x;
    if (idx >= TM * 256) return;
    int c = idx % 256; int n = idx / 256;
    const float* hr = h1 + (size_t)n * 512;
    float acc = 0.f;
    for (int d = 0; d < 512; ++d) acc = fmaf(hr[d], ws2[d * 256 + c], acc);
    Y2[idx] = acc;
}

__global__ void s2_k(const float* __restrict__ Y2, float* __restrict__ S2) {
    int idx = blockIdx.x * 256 + threadIdx.x;
    if (idx >= T_EX * 256) return;
    int c = idx % 256, t = idx / 256;
    float acc = 0.f;
    for (int m = 0; m < MM; ++m) acc += Y2[(m * T_EX + t) * 256 + c];
    S2[idx] = acc;
}

__global__ void h2_k(const float* __restrict__ Y2, const float* __restrict__ S2,
                     const float* __restrict__ bs2, float* __restrict__ h2) {
    int idx = blockIdx.x * 256 + threadIdx.x;
    if (idx >= TM * 256) return;
    int c = idx % 256; int n = idx / 256;
    int t = n % T_EX;
    float val = S2[t * 256 + c] + bs2[c];
    if (t == 0) val -= Y2[idx];
    h2[idx] = lrelu(val);
}

// ---------- V1[d][m] = max_t h2[(m*16+t)][d];  Vx = V1 + X_hat ----------
__global__ void v1vx_k(const float* __restrict__ h2, const float* __restrict__ xhat,
                       float* __restrict__ V1, float* __restrict__ Vx) {
    int idx = blockIdx.x * 256 + threadIdx.x;
    if (idx >= DD * MM) return;
    int m = idx % MM, d = idx / MM;
    float mx = -INFINITY;
    for (int t = 0; t < T_EX; ++t) mx = fmaxf(mx, h2[(m * T_EX + t) * 256 + d]);
    V1[idx] = mx;
    Vx[idx] = mx + xhat[idx];
}

// ---------- out[o][m] = sum_i W[o][i]*Vin[i][m] + bias[o]  (G and Hh) ----------
__global__ void lin88_k(const float* __restrict__ W, const float* __restrict__ bias,
                        const float* __restrict__ Vin, float* __restrict__ out) {
    int idx = blockIdx.x * 256 + threadIdx.x;
    if (idx >= DD * MM) return;
    int m = idx % MM, o = idx / MM;
    const float* wr = W + o * 256;
    float acc = bias[o];
    for (int i = 0; i < 256; ++i) acc = fmaf(wr[i], Vin[i * MM + m], acc);
    out[idx] = acc;
}

// ---------- Smat[j][i] = sum_c Hh[c][j]*G[c][i] ----------
__global__ void smat_k(const float* __restrict__ Hh, const float* __restrict__ G,
                       float* __restrict__ Sm) {
    int idx = blockIdx.x * 256 + threadIdx.x;
    if (idx >= MM * MM) return;
    int i = idx % MM, j = idx / MM;
    float acc = 0.f;
    for (int c = 0; c < 256; ++c) acc = fmaf(Hh[c * MM + j], G[c * MM + i], acc);
    Sm[idx] = acc;
}

// ---------- row softmax (axis=1) ----------
__global__ void softmax_k(const float* __restrict__ S, float* __restrict__ A2) {
    int j = blockIdx.x; int i = threadIdx.x;
    __shared__ float red[128];
    float val = (i < MM) ? S[j * MM + i] : -INFINITY;
    red[i] = val; __syncthreads();
    for (int s = 64; s > 0; s >>= 1) {
        if (i < s) red[i] = fmaxf(red[i], red[i + s]);
        __syncthreads();
    }
    float mx = red[0]; __syncthreads();
    float e = (i < MM) ? expf(val - mx) : 0.f;
    red[i] = e; __syncthreads();
    for (int s = 64; s > 0; s >>= 1) {
        if (i < s) red[i] += red[i + s];
        __syncthreads();
    }
    float inv = 1.f / red[0];
    if (i < MM) A2[j * MM + i] = e * inv;
}

// ---------- t1[m][c] = sum_d V1[d][m]*wc1[d][c]  (88x384) ----------
__global__ void t1_k(const float* __restrict__ V1, const float* __restrict__ wc1,
                     float* __restrict__ t1) {
    int idx = blockIdx.x * 256 + threadIdx.x;
    if (idx >= MM * 384) return;
    int c = idx % 384, m = idx / 384;
    float acc = 0.f;
    for (int d = 0; d < 256; ++d) acc = fmaf(V1[d * MM + m], wc1[d * 384 + c], acc);
    t1[idx] = acc;
}

// ---------- c1[j][c] = lrelu(sum_i A2[j][i]*t1[i][c] + bc1[c]) ----------
__global__ void c1_k(const float* __restrict__ A2, const float* __restrict__ t1,
                     const float* __restrict__ bc1, float* __restrict__ c1) {
    int idx = blockIdx.x * 256 + threadIdx.x;
    if (idx >= MM * 384) return;
    int c = idx % 384, j = idx / 384;
    float acc = bc1[c];
    for (int i = 0; i < MM; ++i) acc = fmaf(A2[j * MM + i], t1[i * 384 + c], acc);
    c1[idx] = lrelu(acc);
}

// ---------- t2[m][c] = sum_d c1[m][d]*wc2[d][c]  (88x256) ----------
__global__ void t2_k(const float* __restrict__ c1, const float* __restrict__ wc2,
                     float* __restrict__ t2) {
    int idx = blockIdx.x * 256 + threadIdx.x;
    if (idx >= MM * 256) return;
    int c = idx % 256, m = idx / 256;
    const float* cr = c1 + m * 384;
    float acc = 0.f;
    for (int d = 0; d < 384; ++d) acc = fmaf(cr[d], wc2[d * 256 + c], acc);
    t2[idx] = acc;
}

// ---------- V2m[j][c] = lrelu(sum_i A2[j][i]*t2[i][c] + bc2[c]) ----------
__global__ void v2_k(const float* __restrict__ A2, const float* __restrict__ t2,
                     const float* __restrict__ bc2, float* __restrict__ V2m) {
    int idx = blockIdx.x * 256 + threadIdx.x;
    if (idx >= MM * 256) return;
    int c = idx % 256, j = idx / 256;
    float acc = bc2[c];
    for (int i = 0; i < MM; ++i) acc = fmaf(A2[j * MM + i], t2[i * 256 + c], acc);
    V2m[idx] = lrelu(acc);
}

// ---------- R = sum_{d,m} Xf[d][m] * V2m[m][d] ----------
__global__ void final_k(const float* __restrict__ Xf, const float* __restrict__ V2m,
                        float* __restrict__ out) {
    __shared__ float red[256];
    float acc = 0.f;
    for (int idx = threadIdx.x; idx < DD * MM; idx += 256) {
        int m = idx % MM, d = idx / MM;
        acc = fmaf(Xf[idx], V2m[m * 256 + d], acc);
    }
    red[threadIdx.x] = acc; __syncthreads();
    for (int s = 128; s > 0; s >>= 1) {
        if (threadIdx.x < s) red[threadIdx.x] += red[threadIdx.x + s];
        __syncthreads();
    }
    if (threadIdx.x == 0) out[0] = red[0];
}

extern "C" void kernel_launch(void* const* d_in, const int* in_sizes, int n_in,
                              void* d_out, int out_size, void* d_ws, size_t ws_size,
                              hipStream_t stream) {
    const float* search = (const float*)d_in[0];
    const float* exemp  = (const float*)d_in[1];
    const float* aw1 = (const float*)d_in[2];  const float* ab1 = (const float*)d_in[3];
    const float* aw2 = (const float*)d_in[4];  const float* ab2 = (const float*)d_in[5];
    const float* aw3 = (const float*)d_in[6];  const float* ab3 = (const float*)d_in[7];
    const float* aw4 = (const float*)d_in[8];  const float* ab4 = (const float*)d_in[9];
    const float* aw5 = (const float*)d_in[10]; const float* ab5 = (const float*)d_in[11];
    const float* wcd = (const float*)d_in[12]; const float* bcd = (const float*)d_in[13];
    const float* wt  = (const float*)d_in[14]; const float* bt  = (const float*)d_in[15];
    const float* ws1 = (const float*)d_in[16]; const float* bs1 = (const float*)d_in[17];
    const float* ws2 = (const float*)d_in[18]; const float* bs2 = (const float*)d_in[19];
    const float* wg  = (const float*)d_in[20]; const float* bg  = (const float*)d_in[21];
    const float* wh  = (const float*)d_in[22]; const float* bh  = (const float*)d_in[23];
    const float* wc1 = (const float*)d_in[24]; const float* bc1 = (const float*)d_in[25];
    const float* wc2 = (const float*)d_in[26]; const float* bc2 = (const float*)d_in[27];

    float* ws = (float*)d_ws;
    float* A  = ws;                 // [0, 7,400,000) floats — big ping buffer
    float* Bb = ws + 7400000;       // [7.4M, 9.2M) floats — pong buffer

    // ---- features (batch 17) ----
    // conv1 -> A  [17,64,95,71]
    {
        int tiles = (H1 * W1 + 255) / 256; // 27
        conv1_k<<<BATCH * C1 * tiles, 256, 0, stream>>>(search, exemp, aw1, ab1, A);
    }
    // pool1 A -> Bb [17,64,47,35]
    {
        int total = BATCH * C1 * H1P * W1P;
        maxpool_k<<<(total + 255) / 256, 256, 0, stream>>>(A, Bb, C1, H1, W1, H1P, W1P);
    }
    // conv2 Bb -> A [17,192,47,35]
    {
        int HW = H1P * W1P; int tiles = (HW + 255) / 256;
        convk<64, 5, 2><<<BATCH * C2 * tiles, 256, 64 * 25 * 4, stream>>>(Bb, aw2, ab2, A, C2, H1P, W1P);
    }
    // pool2 A -> Bb [17,192,23,17]
    {
        int total = BATCH * C2 * H2P * W2P;
        maxpool_k<<<(total + 255) / 256, 256, 0, stream>>>(A, Bb, C2, H1P, W1P, H2P, W2P);
    }
    // conv3 Bb -> A [17,384,23,17]
    {
        int HW = H2P * W2P; int tiles = (HW + 255) / 256;
        convk<192, 3, 1><<<BATCH * C3 * tiles, 256, 192 * 9 * 4, stream>>>(Bb, aw3, ab3, A, C3, H2P, W2P);
    }
    // conv4 A -> Bb [17,256,23,17]
    {
        int HW = H2P * W2P; int tiles = (HW + 255) / 256;
        convk<384, 3, 1><<<BATCH * C45 * tiles, 256, 384 * 9 * 4, stream>>>(A, aw4, ab4, Bb, C45, H2P, W2P);
    }
    // conv5 Bb -> A [17,256,23,17]
    {
        int HW = H2P * W2P; int tiles = (HW + 255) / 256;
        convk<256, 3, 1><<<BATCH * C45 * tiles, 256, 256 * 9 * 4, stream>>>(Bb, aw5, ab5, A, C45, H2P, W2P);
    }
    // pool5 A -> Bb [17,256,11,8]  == P
    {
        int total = BATCH * C45 * H5P * W5P;
        maxpool_k<<<(total + 255) / 256, 256, 0, stream>>>(A, Bb, C45, H2P, W2P, H5P, W5P);
    }

    float* P   = Bb;                // [17,256,88]; Xf = P, Zf = P + 22528
    float* Xf  = P;

    // ---- small buffers live in A (conv activations no longer needed) ----
    float* v_   = A + 0;            // 256
    float* xhat = A + 1024;         // 22528
    float* Y1   = A + 24576;        // 720896
    float* S1   = A + 745472;       // 8192
    float* h1   = A + 753664;       // 720896
    float* Y2   = A + 1474560;      // 360448
    float* S2   = A + 1835008;      // 4096
    float* h2   = A + 1839104;      // 360448
    float* V1   = A + 2199552;      // 22528
    float* Vx   = A + 2222080;      // 22528
    float* G    = A + 2244608;      // 22528
    float* Hh   = A + 2267136;      // 22528
    float* Sm   = A + 2289664;      // 7744
    float* A2   = A + 2297408;      // 7744
    float* t1   = A + 2305152;      // 33792
    float* c1   = A + 2338944;      // 33792
    float* t2   = A + 2372736;      // 22528
    float* V2m  = A + 2395264;      // 22528

    // conv_deconv branch
    cdv_k<<<256, 128, 0, stream>>>(Xf, wcd, bcd, v_);
    xhat_k<<<(DD * MM + 255) / 256, 256, 0, stream>>>(v_, wt, bt, xhat);

    // st GCN (A1 applied in structured form)
    y1_k<<<(TM * 512 + 255) / 256, 256, 0, stream>>>(P, ws1, Y1);
    s1_k<<<(T_EX * 512 + 255) / 256, 256, 0, stream>>>(Y1, S1);
    h1_k<<<(TM * 512 + 255) / 256, 256, 0, stream>>>(Y1, S1, bs1, h1);
    y2_k<<<(TM * 256 + 255) / 256, 256, 0, stream>>>(h1, ws2, Y2);
    s2_k<<<(T_EX * 256 + 255) / 256, 256, 0, stream>>>(Y2, S2);
    h2_k<<<(TM * 256 + 255) / 256, 256, 0, stream>>>(Y2, S2, bs2, h2);
    v1vx_k<<<(DD * MM + 255) / 256, 256, 0, stream>>>(h2, xhat, V1, Vx);

    // dynamic graph
    lin88_k<<<(DD * MM + 255) / 256, 256, 0, stream>>>(wg, bg, Vx, G);
    lin88_k<<<(DD * MM + 255) / 256, 256, 0, stream>>>(wh, bh, Vx, Hh);
    smat_k<<<(MM * MM + 255) / 256, 256, 0, stream>>>(Hh, G, Sm);
    softmax_k<<<MM, 128, 0, stream>>>(Sm, A2);

    // ct GCN
    t1_k<<<(MM * 384 + 255) / 256, 256, 0, stream>>>(V1, wc1, t1);
    c1_k<<<(MM * 384 + 255) / 256, 256, 0, stream>>>(A2, t1, bc1, c1);
    t2_k<<<(MM * 256 + 255) / 256, 256, 0, stream>>>(c1, wc2, t2);
    v2_k<<<(MM * 256 + 255) / 256, 256, 0, stream>>>(A2, t2, bc2, V2m);

    // final correlation -> scalar
    final_k<<<1, 256, 0, stream>>>(Xf, V2m, (float*)d_out);
}

// Round 2
// 2027.742 us; speedup vs baseline: 4.7903x; 4.7903x over previous
//
#include <hip/hip_runtime.h>
#include <hip/hip_bf16.h>
#include <math.h>

// ---------- dims ----------
#define BATCH 17          // search + 16 exemplars
#define T_EX 16
#define H0 383
#define W0 287
#define C1 64
#define H1 95
#define W1 71
#define H1P 47
#define W1P 35
#define C2 192
#define H2P 23
#define W2P 17
#define C3 384
#define C45 256
#define H5P 11
#define W5P 8
#define DD 256
#define MM 88            // 11*8
#define TM 1408          // 16*88

__device__ __forceinline__ float lrelu(float v) { return v > 0.f ? v : 0.01f * v; }

// ====================================================================
// Implicit-GEMM conv: BM=64 oc x BN=64 spatial, BK=16, 256 thr, 4x4/thread.
// Fused bias + relu. KGUARD for KSZ not multiple of 16 (conv1).
// SPLIT: batch 0 comes from in0 (search), rest from in1 (exemplars).
// ====================================================================
template <int KH, int KW, int STRIDE, int PAD, bool KGUARD, bool SPLIT>
__global__ __launch_bounds__(256) void conv_igemm(
    const float* __restrict__ in0, const float* __restrict__ in1,
    const float* __restrict__ w, const float* __restrict__ bias,
    float* __restrict__ out, int CIN, int Hin, int Win, int Hout, int Wout) {
    const int KHW = KH * KW;
    const int KSZ = CIN * KHW;
    const int HW = Hout * Wout;
    const int tid = threadIdx.x;
    const int n_blk = blockIdx.x * 64;
    const int oc0 = blockIdx.y * 64;
    const int b = blockIdx.z;
    const int COUT = gridDim.y * 64;

    const float* inb;
    if (SPLIT) inb = (b == 0) ? in0 : in1 + (size_t)(b - 1) * CIN * Hin * Win;
    else       inb = in0 + (size_t)b * CIN * Hin * Win;

    __shared__ float As[16][68];   // [k][m], padded to break write conflicts
    __shared__ float Bs[16][64];   // [k][n]

    // ---- B (input patch) load mapping: thread -> fixed n, 4 k-rows ----
    const int bn = tid & 63;
    const int bkb = tid >> 6;              // k rows bkb, bkb+4, bkb+8, bkb+12
    const int n_g = n_blk + bn;
    const int oy = n_g / Wout, ox = n_g % Wout;
    const int iy0 = oy * STRIDE - PAD, ix0 = ox * STRIDE - PAD;

    // ---- A (weight) load mapping: thread -> fixed m, 4 consecutive k ----
    const int am = tid >> 2;
    const int ak = (tid & 3) * 4;
    const float* wrow = w + (size_t)(oc0 + am) * KSZ + ak;

    float acc[4][4];
#pragma unroll
    for (int i = 0; i < 4; ++i)
#pragma unroll
        for (int j = 0; j < 4; ++j) acc[i][j] = 0.f;

    const int m0 = (tid >> 4) * 4;
    const int n0 = (tid & 15) * 4;

    for (int kk0 = 0; kk0 < KSZ; kk0 += 16) {
        // stage weights
#pragma unroll
        for (int j = 0; j < 4; ++j) {
            float v = 0.f;
            if (!KGUARD || (kk0 + ak + j) < KSZ) v = wrow[kk0 + j];
            As[ak + j][am] = v;
        }
        // stage input patches (im2col gather)
#pragma unroll
        for (int p = 0; p < 4; ++p) {
            const int krow = bkb + p * 4;
            const int kg = kk0 + krow;
            float v = 0.f;
            if (!KGUARD || kg < KSZ) {
                const int ic = kg / KHW;
                const int r = kg - ic * KHW;
                const int ky = r / KW;
                const int kx = r - ky * KW;
                const int iy = iy0 + ky, ix = ix0 + kx;
                if ((unsigned)iy < (unsigned)Hin && (unsigned)ix < (unsigned)Win)
                    v = inb[(ic * Hin + iy) * Win + ix];
            }
            Bs[krow][bn] = v;
        }
        __syncthreads();
#pragma unroll
        for (int kk = 0; kk < 16; ++kk) {
            const float a0 = As[kk][m0], a1 = As[kk][m0 + 1],
                        a2 = As[kk][m0 + 2], a3 = As[kk][m0 + 3];
            const float b0 = Bs[kk][n0], b1 = Bs[kk][n0 + 1],
                        b2 = Bs[kk][n0 + 2], b3 = Bs[kk][n0 + 3];
            acc[0][0] = fmaf(a0, b0, acc[0][0]);
            acc[0][1] = fmaf(a0, b1, acc[0][1]);
            acc[0][2] = fmaf(a0, b2, acc[0][2]);
            acc[0][3] = fmaf(a0, b3, acc[0][3]);
            acc[1][0] = fmaf(a1, b0, acc[1][0]);
            acc[1][1] = fmaf(a1, b1, acc[1][1]);
            acc[1][2] = fmaf(a1, b2, acc[1][2]);
            acc[1][3] = fmaf(a1, b3, acc[1][3]);
            acc[2][0] = fmaf(a2, b0, acc[2][0]);
            acc[2][1] = fmaf(a2, b1, acc[2][1]);
            acc[2][2] = fmaf(a2, b2, acc[2][2]);
            acc[2][3] = fmaf(a2, b3, acc[2][3]);
            acc[3][0] = fmaf(a3, b0, acc[3][0]);
            acc[3][1] = fmaf(a3, b1, acc[3][1]);
            acc[3][2] = fmaf(a3, b2, acc[3][2]);
            acc[3][3] = fmaf(a3, b3, acc[3][3]);
        }
        __syncthreads();
    }

    // epilogue: bias + relu + store
#pragma unroll
    for (int i = 0; i < 4; ++i) {
        const int oc = oc0 + m0 + i;
        const float bia = bias[oc];
        float* orow = out + (size_t)(b * COUT + oc) * HW;
#pragma unroll
        for (int j = 0; j < 4; ++j) {
            const int ng = n_blk + n0 + j;
            if (ng < HW) orow[ng] = fmaxf(acc[i][j] + bia, 0.f);
        }
    }
}

// ---------- maxpool k3 s2 VALID ----------
__global__ void maxpool_k(const float* __restrict__ in, float* __restrict__ out,
                          int C, int Hin, int Win, int Hout, int Wout) {
    int total = BATCH * C * Hout * Wout;
    int idx = blockIdx.x * 256 + threadIdx.x;
    if (idx >= total) return;
    int x = idx % Wout; int t = idx / Wout;
    int y = t % Hout; t /= Hout;
    int c = t % C; int b = t / C;
    const float* p = in + ((size_t)(b * C + c) * Hin + 2 * y) * Win + 2 * x;
    float m = p[0];
    m = fmaxf(m, p[1]); m = fmaxf(m, p[2]);
    m = fmaxf(m, p[Win]); m = fmaxf(m, p[Win + 1]); m = fmaxf(m, p[Win + 2]);
    m = fmaxf(m, p[2 * Win]); m = fmaxf(m, p[2 * Win + 1]); m = fmaxf(m, p[2 * Win + 2]);
    out[idx] = m;
}

// ---------- conv_deconv: conv1d(k3,p1) + global max over positions -> v[256] ----------
__global__ void cdv_k(const float* __restrict__ Xf, const float* __restrict__ wcd,
                      const float* __restrict__ bcd, float* __restrict__ v) {
    int c = blockIdx.x;       // 256
    int m = threadIdx.x;      // 128 threads
    float val = -INFINITY;
    if (m < MM) {
        float acc = bcd[c];
        const float* wrow = wcd + c * 256 * 3;
        for (int i = 0; i < 256; ++i) {
            const float* xr = Xf + i * MM;
            float w0 = wrow[i * 3 + 0], w1 = wrow[i * 3 + 1], w2 = wrow[i * 3 + 2];
            if (m > 0) acc = fmaf(w0, xr[m - 1], acc);
            acc = fmaf(w1, xr[m], acc);
            if (m < MM - 1) acc = fmaf(w2, xr[m + 1], acc);
        }
        val = acc;
    }
    __shared__ float red[128];
    red[threadIdx.x] = val;
    __syncthreads();
    for (int s = 64; s > 0; s >>= 1) {
        if (threadIdx.x < s) red[threadIdx.x] = fmaxf(red[threadIdx.x], red[threadIdx.x + s]);
        __syncthreads();
    }
    if (threadIdx.x == 0) v[c] = red[0];
}

// ---------- X_hat[o,k] = sum_i v[i]*wt[i,o,k] + bt[o] ----------
__global__ void xhat_k(const float* __restrict__ v, const float* __restrict__ wt,
                       const float* __restrict__ bt, float* __restrict__ xhat) {
    __shared__ float lv[256];
    for (int j = threadIdx.x; j < 256; j += 256) lv[j] = v[j];
    __syncthreads();
    int idx = blockIdx.x * 256 + threadIdx.x;
    if (idx >= DD * MM) return;
    int k = idx % MM, o = idx / MM;
    float acc = bt[o];
    for (int i = 0; i < 256; ++i) acc = fmaf(lv[i], wt[(i * 256 + o) * MM + k], acc);
    xhat[idx] = acc;
}

// ---------- Y1 = nodes @ ws1 : [1408,512] ----------
__global__ void y1_k(const float* __restrict__ P, const float* __restrict__ ws1,
                     float* __restrict__ Y1) {
    int idx = blockIdx.x * 256 + threadIdx.x;
    if (idx >= TM * 512) return;
    int c = idx % 512; int n = idx / 512;
    int t = n % T_EX, m = n / T_EX;
    const float* node = P + (size_t)(1 + t) * (DD * MM) + m;
    float acc = 0.f;
    for (int d = 0; d < 256; ++d) acc = fmaf(node[d * MM], ws1[d * 512 + c], acc);
    Y1[idx] = acc;
}

__global__ void s1_k(const float* __restrict__ Y1, float* __restrict__ S1) {
    int idx = blockIdx.x * 256 + threadIdx.x;
    if (idx >= T_EX * 512) return;
    int c = idx % 512, t = idx / 512;
    float acc = 0.f;
    for (int m = 0; m < MM; ++m) acc += Y1[(m * T_EX + t) * 512 + c];
    S1[idx] = acc;
}

__global__ void h1_k(const float* __restrict__ Y1, const float* __restrict__ S1,
                     const float* __restrict__ bs1, float* __restrict__ h1) {
    int idx = blockIdx.x * 256 + threadIdx.x;
    if (idx >= TM * 512) return;
    int c = idx % 512; int n = idx / 512;
    int t = n % T_EX;
    float val = S1[t * 512 + c] + bs1[c];
    if (t == 0) val -= Y1[idx];
    h1[idx] = lrelu(val);
}

__global__ void y2_k(const float* __restrict__ h1, const float* __restrict__ ws2,
                     float* __restrict__ Y2) {
    int idx = blockIdx.x * 256 + threadIdx.x;
    if (idx >= TM * 256) return;
    int c = idx % 256; int n = idx / 256;
    const float* hr = h1 + (size_t)n * 512;
    float acc = 0.f;
    for (int d = 0; d < 512; ++d) acc = fmaf(hr[d], ws2[d * 256 + c], acc);
    Y2[idx] = acc;
}

__global__ void s2_k(const float* __restrict__ Y2, float* __restrict__ S2) {
    int idx = blockIdx.x * 256 + threadIdx.x;
    if (idx >= T_EX * 256) return;
    int c = idx % 256, t = idx / 256;
    float acc = 0.f;
    for (int m = 0; m < MM; ++m) acc += Y2[(m * T_EX + t) * 256 + c];
    S2[idx] = acc;
}

__global__ void h2_k(const float* __restrict__ Y2, const float* __restrict__ S2,
                     const float* __restrict__ bs2, float* __restrict__ h2) {
    int idx = blockIdx.x * 256 + threadIdx.x;
    if (idx >= TM * 256) return;
    int c = idx % 256; int n = idx / 256;
    int t = n % T_EX;
    float val = S2[t * 256 + c] + bs2[c];
    if (t == 0) val -= Y2[idx];
    h2[idx] = lrelu(val);
}

__global__ void v1vx_k(const float* __restrict__ h2, const float* __restrict__ xhat,
                       float* __restrict__ V1, float* __restrict__ Vx) {
    int idx = blockIdx.x * 256 + threadIdx.x;
    if (idx >= DD * MM) return;
    int m = idx % MM, d = idx / MM;
    float mx = -INFINITY;
    for (int t = 0; t < T_EX; ++t) mx = fmaxf(mx, h2[(m * T_EX + t) * 256 + d]);
    V1[idx] = mx;
    Vx[idx] = mx + xhat[idx];
}

__global__ void lin88_k(const float* __restrict__ W, const float* __restrict__ bias,
                        const float* __restrict__ Vin, float* __restrict__ out) {
    int idx = blockIdx.x * 256 + threadIdx.x;
    if (idx >= DD * MM) return;
    int m = idx % MM, o = idx / MM;
    const float* wr = W + o * 256;
    float acc = bias[o];
    for (int i = 0; i < 256; ++i) acc = fmaf(wr[i], Vin[i * MM + m], acc);
    out[idx] = acc;
}

__global__ void smat_k(const float* __restrict__ Hh, const float* __restrict__ G,
                       float* __restrict__ Sm) {
    int idx = blockIdx.x * 256 + threadIdx.x;
    if (idx >= MM * MM) return;
    int i = idx % MM, j = idx / MM;
    float acc = 0.f;
    for (int c = 0; c < 256; ++c) acc = fmaf(Hh[c * MM + j], G[c * MM + i], acc);
    Sm[idx] = acc;
}

__global__ void softmax_k(const float* __restrict__ S, float* __restrict__ A2) {
    int j = blockIdx.x; int i = threadIdx.x;
    __shared__ float red[128];
    float val = (i < MM) ? S[j * MM + i] : -INFINITY;
    red[i] = val; __syncthreads();
    for (int s = 64; s > 0; s >>= 1) {
        if (i < s) red[i] = fmaxf(red[i], red[i + s]);
        __syncthreads();
    }
    float mx = red[0]; __syncthreads();
    float e = (i < MM) ? expf(val - mx) : 0.f;
    red[i] = e; __syncthreads();
    for (int s = 64; s > 0; s >>= 1) {
        if (i < s) red[i] += red[i + s];
        __syncthreads();
    }
    float inv = 1.f / red[0];
    if (i < MM) A2[j * MM + i] = e * inv;
}

__global__ void t1_k(const float* __restrict__ V1, const float* __restrict__ wc1,
                     float* __restrict__ t1) {
    int idx = blockIdx.x * 256 + threadIdx.x;
    if (idx >= MM * 384) return;
    int c = idx % 384, m = idx / 384;
    float acc = 0.f;
    for (int d = 0; d < 256; ++d) acc = fmaf(V1[d * MM + m], wc1[d * 384 + c], acc);
    t1[idx] = acc;
}

__global__ void c1_k(const float* __restrict__ A2, const float* __restrict__ t1,
                     const float* __restrict__ bc1, float* __restrict__ c1) {
    int idx = blockIdx.x * 256 + threadIdx.x;
    if (idx >= MM * 384) return;
    int c = idx % 384, j = idx / 384;
    float acc = bc1[c];
    for (int i = 0; i < MM; ++i) acc = fmaf(A2[j * MM + i], t1[i * 384 + c], acc);
    c1[idx] = lrelu(acc);
}

__global__ void t2_k(const float* __restrict__ c1, const float* __restrict__ wc2,
                     float* __restrict__ t2) {
    int idx = blockIdx.x * 256 + threadIdx.x;
    if (idx >= MM * 256) return;
    int c = idx % 256, m = idx / 256;
    const float* cr = c1 + m * 384;
    float acc = 0.f;
    for (int d = 0; d < 384; ++d) acc = fmaf(cr[d], wc2[d * 256 + c], acc);
    t2[idx] = acc;
}

__global__ void v2_k(const float* __restrict__ A2, const float* __restrict__ t2,
                     const float* __restrict__ bc2, float* __restrict__ V2m) {
    int idx = blockIdx.x * 256 + threadIdx.x;
    if (idx >= MM * 256) return;
    int c = idx % 256, j = idx / 256;
    float acc = bc2[c];
    for (int i = 0; i < MM; ++i) acc = fmaf(A2[j * MM + i], t2[i * 256 + c], acc);
    V2m[idx] = lrelu(acc);
}

__global__ void final_k(const float* __restrict__ Xf, const float* __restrict__ V2m,
                        float* __restrict__ out) {
    __shared__ float red[256];
    float acc = 0.f;
    for (int idx = threadIdx.x; idx < DD * MM; idx += 256) {
        int m = idx % MM, d = idx / MM;
        acc = fmaf(Xf[idx], V2m[m * 256 + d], acc);
    }
    red[threadIdx.x] = acc; __syncthreads();
    for (int s = 128; s > 0; s >>= 1) {
        if (threadIdx.x < s) red[threadIdx.x] += red[threadIdx.x + s];
        __syncthreads();
    }
    if (threadIdx.x == 0) out[0] = red[0];
}

extern "C" void kernel_launch(void* const* d_in, const int* in_sizes, int n_in,
                              void* d_out, int out_size, void* d_ws, size_t ws_size,
                              hipStream_t stream) {
    const float* search = (const float*)d_in[0];
    const float* exemp  = (const float*)d_in[1];
    const float* aw1 = (const float*)d_in[2];  const float* ab1 = (const float*)d_in[3];
    const float* aw2 = (const float*)d_in[4];  const float* ab2 = (const float*)d_in[5];
    const float* aw3 = (const float*)d_in[6];  const float* ab3 = (const float*)d_in[7];
    const float* aw4 = (const float*)d_in[8];  const float* ab4 = (const float*)d_in[9];
    const float* aw5 = (const float*)d_in[10]; const float* ab5 = (const float*)d_in[11];
    const float* wcd = (const float*)d_in[12]; const float* bcd = (const float*)d_in[13];
    const float* wt  = (const float*)d_in[14]; const float* bt  = (const float*)d_in[15];
    const float* ws1 = (const float*)d_in[16]; const float* bs1 = (const float*)d_in[17];
    const float* ws2 = (const float*)d_in[18]; const float* bs2 = (const float*)d_in[19];
    const float* wg  = (const float*)d_in[20]; const float* bg  = (const float*)d_in[21];
    const float* wh  = (const float*)d_in[22]; const float* bh  = (const float*)d_in[23];
    const float* wc1 = (const float*)d_in[24]; const float* bc1 = (const float*)d_in[25];
    const float* wc2 = (const float*)d_in[26]; const float* bc2 = (const float*)d_in[27];

    float* ws = (float*)d_ws;
    float* A  = ws;                 // big ping buffer
    float* Bb = ws + 7400000;       // pong buffer

    // ---- features (batch 17), implicit-GEMM convs ----
    // conv1 -> A [17,64,95,71]
    conv_igemm<11, 11, 4, 2, true, true>
        <<<dim3((H1 * W1 + 63) / 64, C1 / 64, BATCH), 256, 0, stream>>>(
            search, exemp, aw1, ab1, A, 3, H0, W0, H1, W1);
    // pool1 A -> Bb [17,64,47,35]
    {
        int total = BATCH * C1 * H1P * W1P;
        maxpool_k<<<(total + 255) / 256, 256, 0, stream>>>(A, Bb, C1, H1, W1, H1P, W1P);
    }
    // conv2 Bb -> A [17,192,47,35]
    conv_igemm<5, 5, 1, 2, false, false>
        <<<dim3((H1P * W1P + 63) / 64, C2 / 64, BATCH), 256, 0, stream>>>(
            Bb, Bb, aw2, ab2, A, 64, H1P, W1P, H1P, W1P);
    // pool2 A -> Bb [17,192,23,17]
    {
        int total = BATCH * C2 * H2P * W2P;
        maxpool_k<<<(total + 255) / 256, 256, 0, stream>>>(A, Bb, C2, H1P, W1P, H2P, W2P);
    }
    // conv3 Bb -> A [17,384,23,17]
    conv_igemm<3, 3, 1, 1, false, false>
        <<<dim3((H2P * W2P + 63) / 64, C3 / 64, BATCH), 256, 0, stream>>>(
            Bb, Bb, aw3, ab3, A, 192, H2P, W2P, H2P, W2P);
    // conv4 A -> Bb [17,256,23,17]
    conv_igemm<3, 3, 1, 1, false, false>
        <<<dim3((H2P * W2P + 63) / 64, C45 / 64, BATCH), 256, 0, stream>>>(
            A, A, aw4, ab4, Bb, 384, H2P, W2P, H2P, W2P);
    // conv5 Bb -> A [17,256,23,17]
    conv_igemm<3, 3, 1, 1, false, false>
        <<<dim3((H2P * W2P + 63) / 64, C45 / 64, BATCH), 256, 0, stream>>>(
            Bb, Bb, aw5, ab5, A, 256, H2P, W2P, H2P, W2P);
    // pool5 A -> Bb [17,256,11,8] == P
    {
        int total = BATCH * C45 * H5P * W5P;
        maxpool_k<<<(total + 255) / 256, 256, 0, stream>>>(A, Bb, C45, H2P, W2P, H5P, W5P);
    }

    float* P   = Bb;                // [17,256,88]; Xf = P
    float* Xf  = P;

    // ---- small buffers live in A ----
    float* v_   = A + 0;
    float* xhat = A + 1024;
    float* Y1   = A + 24576;
    float* S1   = A + 745472;
    float* h1   = A + 753664;
    float* Y2   = A + 1474560;
    float* S2   = A + 1835008;
    float* h2   = A + 1839104;
    float* V1   = A + 2199552;
    float* Vx   = A + 2222080;
    float* G    = A + 2244608;
    float* Hh   = A + 2267136;
    float* Sm   = A + 2289664;
    float* A2   = A + 2297408;
    float* t1   = A + 2305152;
    float* c1   = A + 2338944;
    float* t2   = A + 2372736;
    float* V2m  = A + 2395264;

    // conv_deconv branch
    cdv_k<<<256, 128, 0, stream>>>(Xf, wcd, bcd, v_);
    xhat_k<<<(DD * MM + 255) / 256, 256, 0, stream>>>(v_, wt, bt, xhat);

    // st GCN (A1 applied in structured form)
    y1_k<<<(TM * 512 + 255) / 256, 256, 0, stream>>>(P, ws1, Y1);
    s1_k<<<(T_EX * 512 + 255) / 256, 256, 0, stream>>>(Y1, S1);
    h1_k<<<(TM * 512 + 255) / 256, 256, 0, stream>>>(Y1, S1, bs1, h1);
    y2_k<<<(TM * 256 + 255) / 256, 256, 0, stream>>>(h1, ws2, Y2);
    s2_k<<<(T_EX * 256 + 255) / 256, 256, 0, stream>>>(Y2, S2);
    h2_k<<<(TM * 256 + 255) / 256, 256, 0, stream>>>(Y2, S2, bs2, h2);
    v1vx_k<<<(DD * MM + 255) / 256, 256, 0, stream>>>(h2, xhat, V1, Vx);

    // dynamic graph
    lin88_k<<<(DD * MM + 255) / 256, 256, 0, stream>>>(wg, bg, Vx, G);
    lin88_k<<<(DD * MM + 255) / 256, 256, 0, stream>>>(wh, bh, Vx, Hh);
    smat_k<<<(MM * MM + 255) / 256, 256, 0, stream>>>(Hh, G, Sm);
    softmax_k<<<MM, 128, 0, stream>>>(Sm, A2);

    // ct GCN
    t1_k<<<(MM * 384 + 255) / 256, 256, 0, stream>>>(V1, wc1, t1);
    c1_k<<<(MM * 384 + 255) / 256, 256, 0, stream>>>(A2, t1, bc1, c1);
    t2_k<<<(MM * 256 + 255) / 256, 256, 0, stream>>>(c1, wc2, t2);
    v2_k<<<(MM * 256 + 255) / 256, 256, 0, stream>>>(A2, t2, bc2, V2m);

    // final correlation -> scalar
    final_k<<<1, 256, 0, stream>>>(Xf, V2m, (float*)d_out);
}

// Round 3
// 1013.620 us; speedup vs baseline: 9.5830x; 2.0005x over previous
//
#include <hip/hip_runtime.h>
#include <hip/hip_bf16.h>
#include <math.h>

// ---------- dims ----------
#define BATCH 17          // search + 16 exemplars
#define T_EX 16
#define H0 383
#define W0 287
#define C1 64
#define H1 95
#define W1 71
#define H1P 47
#define W1P 35
#define C2 192
#define H2P 23
#define W2P 17
#define C3 384
#define C45 256
#define H5P 11
#define W5P 8
#define DD 256
#define MM 88            // 11*8
#define TM 1408          // 16*88

typedef unsigned short ushort_t;
typedef __attribute__((ext_vector_type(8))) short short8;
typedef __attribute__((ext_vector_type(4))) float f32x4;

__device__ __forceinline__ float lrelu(float v) { return v > 0.f ? v : 0.01f * v; }

__device__ __forceinline__ ushort_t f2bf(float f) {
    unsigned int u = __float_as_uint(f);
    unsigned int r = (u + 0x7fffu + ((u >> 16) & 1u)) >> 16;
    return (ushort_t)r;
}
__device__ __forceinline__ float b2f(ushort_t b) {
    return __uint_as_float(((unsigned int)b) << 16);
}

// ====================================================================
// Weight prep: fp32 [COUT][KSZ] -> bf16 MFMA staging tiles.
// Tile layout: [ocb][ks][chunk=k8*64+m][8], chunk holds
// w[ocb*64+m][ks*32 + k8*8 + j], zero-padded past KSZ.
// ====================================================================
__global__ void wprep_k(const float* __restrict__ w, ushort_t* __restrict__ out,
                        int KSZ, int NKS, int nchunks) {
    int idx = blockIdx.x * 256 + threadIdx.x;
    if (idx >= nchunks) return;
    int c = idx & 255;
    int rest = idx >> 8;
    int ks = rest % NKS;
    int ocb = rest / NKS;
    int k8 = c >> 6, m = c & 63;
    int oc = ocb * 64 + m;
    int kbase = ks * 32 + k8 * 8;
    const float* wrow = w + (size_t)oc * KSZ;
    ushort_t* o = out + (size_t)idx * 8;
#pragma unroll
    for (int j = 0; j < 8; ++j) {
        int kg = kbase + j;
        float v = (kg < KSZ) ? wrow[kg] : 0.f;
        o[j] = f2bf(v);
    }
}

// ====================================================================
// bf16 MFMA implicit-GEMM conv. BM=64 oc x BN=64 spatial x BK=32.
// 4 waves; wave wv computes rows [wv*16, wv*16+16) x 64 cols (4 MFMAs/step).
// LDS chunk-major: chunk (k8, r) at (k8*64+r)*8 bf16 -> quad-contiguous
// ds_read_b128 fragments. Output bf16, fused bias+relu.
// ====================================================================
template <int KH, int KW, int STRIDE, int PAD, bool KGUARD, bool SPLIT, bool INF32>
__global__ __launch_bounds__(256) void conv_mfma(
    const void* __restrict__ in0v, const void* __restrict__ in1v,
    const ushort_t* __restrict__ wt, const float* __restrict__ bias,
    ushort_t* __restrict__ out, int CIN, int Hin, int Win, int Hout, int Wout,
    int KSZ, int NKS) {
    constexpr int KHW = KH * KW;
    const int tid = threadIdx.x;
    const int wv = tid >> 6, lane = tid & 63;
    const int HW = Hout * Wout;
    const int n_blk = blockIdx.x * 64;
    const int ocb = blockIdx.y;
    const int COUT = gridDim.y * 64;
    const int b = blockIdx.z;

    const float* inf = nullptr;
    const ushort_t* inu = nullptr;
    if (INF32) {
        if (SPLIT)
            inf = (b == 0) ? (const float*)in0v
                           : (const float*)in1v + (size_t)(b - 1) * CIN * Hin * Win;
        else
            inf = (const float*)in0v + (size_t)b * CIN * Hin * Win;
    } else {
        inu = (const ushort_t*)in0v + (size_t)b * CIN * Hin * Win;
    }

    __shared__ ushort_t As[2048];   // 64 rows x 32 k, chunk-major, 4 KB
    __shared__ ushort_t Bs[2048];

    // B-gather spatial coords (lane = n within tile)
    const int n_g = n_blk + lane;
    const int oy = n_g / Wout, ox = n_g % Wout;
    const int iy0 = oy * STRIDE - PAD, ix0 = ox * STRIDE - PAD;

    f32x4 acc[4];
#pragma unroll
    for (int cn = 0; cn < 4; ++cn) acc[cn] = (f32x4){0.f, 0.f, 0.f, 0.f};

    const ushort_t* wblk = wt + (size_t)ocb * NKS * 2048;

    for (int ks = 0; ks < NKS; ++ks) {
        // ---- stage A: coalesced 16B per thread ----
        {
            const short8 aval = *(const short8*)(wblk + (size_t)ks * 2048 + tid * 8);
            *(short8*)&As[tid * 8] = aval;
        }
        // ---- stage B: im2col gather + fp->bf16 ----
        {
            const int kbase = ks * 32 + wv * 8;
            short8 pk;
#pragma unroll
            for (int j = 0; j < 8; ++j) {
                int kg = kbase + j;
                float v = 0.f;
                if (!KGUARD || kg < KSZ) {
                    int ic = kg / KHW;
                    int r = kg - ic * KHW;
                    int ky = r / KW;
                    int kx = r - ky * KW;
                    int iy = iy0 + ky, ix = ix0 + kx;
                    if ((unsigned)iy < (unsigned)Hin && (unsigned)ix < (unsigned)Win) {
                        size_t off = ((size_t)ic * Hin + iy) * Win + ix;
                        v = INF32 ? inf[off] : b2f(inu[off]);
                    }
                }
                pk[j] = (short)f2bf(v);
            }
            *(short8*)&Bs[tid * 8] = pk;
        }
        __syncthreads();
        {
            const int quad = lane >> 4, l16 = lane & 15;
            const short8 af = *(const short8*)&As[(quad * 64 + wv * 16 + l16) * 8];
#pragma unroll
            for (int cn = 0; cn < 4; ++cn) {
                const short8 bfr = *(const short8*)&Bs[(quad * 64 + cn * 16 + l16) * 8];
                acc[cn] = __builtin_amdgcn_mfma_f32_16x16x32_bf16(af, bfr, acc[cn], 0, 0, 0);
            }
        }
        __syncthreads();
    }

    // ---- epilogue: bias + relu + bf16 store ----
    const int quad = lane >> 4, l16 = lane & 15;
#pragma unroll
    for (int cn = 0; cn < 4; ++cn) {
        int n = n_blk + cn * 16 + l16;
        if (n < HW) {
#pragma unroll
            for (int reg = 0; reg < 4; ++reg) {
                int oc = ocb * 64 + wv * 16 + quad * 4 + reg;
                float v = acc[cn][reg] + bias[oc];
                v = fmaxf(v, 0.f);
                out[((size_t)b * COUT + oc) * HW + n] = f2bf(v);
            }
        }
    }
}

// ---------- maxpool k3 s2 VALID on bf16; optional fp32 output ----------
template <bool OUTF32>
__global__ void maxpool_bf(const ushort_t* __restrict__ in, void* __restrict__ outv,
                           int C, int Hin, int Win, int Hout, int Wout) {
    int total = BATCH * C * Hout * Wout;
    int idx = blockIdx.x * 256 + threadIdx.x;
    if (idx >= total) return;
    int x = idx % Wout; int t = idx / Wout;
    int y = t % Hout; t /= Hout;
    int c = t % C; int b = t / C;
    const ushort_t* p = in + ((size_t)(b * C + c) * Hin + 2 * y) * Win + 2 * x;
    float m = b2f(p[0]);
    m = fmaxf(m, b2f(p[1])); m = fmaxf(m, b2f(p[2]));
    m = fmaxf(m, b2f(p[Win])); m = fmaxf(m, b2f(p[Win + 1])); m = fmaxf(m, b2f(p[Win + 2]));
    m = fmaxf(m, b2f(p[2 * Win])); m = fmaxf(m, b2f(p[2 * Win + 1])); m = fmaxf(m, b2f(p[2 * Win + 2]));
    if (OUTF32) ((float*)outv)[idx] = m;
    else        ((ushort_t*)outv)[idx] = f2bf(m);   // exact (value already bf16)
}

// ---------- conv_deconv: conv1d(k3,p1) + global max over positions -> v[256] ----------
__global__ void cdv_k(const float* __restrict__ Xf, const float* __restrict__ wcd,
                      const float* __restrict__ bcd, float* __restrict__ v) {
    int c = blockIdx.x;
    int m = threadIdx.x;
    float val = -INFINITY;
    if (m < MM) {
        float acc = bcd[c];
        const float* wrow = wcd + c * 256 * 3;
        for (int i = 0; i < 256; ++i) {
            const float* xr = Xf + i * MM;
            float w0 = wrow[i * 3 + 0], w1 = wrow[i * 3 + 1], w2 = wrow[i * 3 + 2];
            if (m > 0) acc = fmaf(w0, xr[m - 1], acc);
            acc = fmaf(w1, xr[m], acc);
            if (m < MM - 1) acc = fmaf(w2, xr[m + 1], acc);
        }
        val = acc;
    }
    __shared__ float red[128];
    red[threadIdx.x] = val;
    __syncthreads();
    for (int s = 64; s > 0; s >>= 1) {
        if (threadIdx.x < s) red[threadIdx.x] = fmaxf(red[threadIdx.x], red[threadIdx.x + s]);
        __syncthreads();
    }
    if (threadIdx.x == 0) v[c] = red[0];
}

__global__ void xhat_k(const float* __restrict__ v, const float* __restrict__ wt,
                       const float* __restrict__ bt, float* __restrict__ xhat) {
    __shared__ float lv[256];
    for (int j = threadIdx.x; j < 256; j += 256) lv[j] = v[j];
    __syncthreads();
    int idx = blockIdx.x * 256 + threadIdx.x;
    if (idx >= DD * MM) return;
    int k = idx % MM, o = idx / MM;
    float acc = bt[o];
    for (int i = 0; i < 256; ++i) acc = fmaf(lv[i], wt[(i * 256 + o) * MM + k], acc);
    xhat[idx] = acc;
}

__global__ void y1_k(const float* __restrict__ P, const float* __restrict__ ws1,
                     float* __restrict__ Y1) {
    int idx = blockIdx.x * 256 + threadIdx.x;
    if (idx >= TM * 512) return;
    int c = idx % 512; int n = idx / 512;
    int t = n % T_EX, m = n / T_EX;
    const float* node = P + (size_t)(1 + t) * (DD * MM) + m;
    float acc = 0.f;
    for (int d = 0; d < 256; ++d) acc = fmaf(node[d * MM], ws1[d * 512 + c], acc);
    Y1[idx] = acc;
}

__global__ void s1_k(const float* __restrict__ Y1, float* __restrict__ S1) {
    int idx = blockIdx.x * 256 + threadIdx.x;
    if (idx >= T_EX * 512) return;
    int c = idx % 512, t = idx / 512;
    float acc = 0.f;
    for (int m = 0; m < MM; ++m) acc += Y1[(m * T_EX + t) * 512 + c];
    S1[idx] = acc;
}

__global__ void h1_k(const float* __restrict__ Y1, const float* __restrict__ S1,
                     const float* __restrict__ bs1, float* __restrict__ h1) {
    int idx = blockIdx.x * 256 + threadIdx.x;
    if (idx >= TM * 512) return;
    int c = idx % 512; int n = idx / 512;
    int t = n % T_EX;
    float val = S1[t * 512 + c] + bs1[c];
    if (t == 0) val -= Y1[idx];
    h1[idx] = lrelu(val);
}

__global__ void y2_k(const float* __restrict__ h1, const float* __restrict__ ws2,
                     float* __restrict__ Y2) {
    int idx = blockIdx.x * 256 + threadIdx.x;
    if (idx >= TM * 256) return;
    int c = idx % 256; int n = idx / 256;
    const float* hr = h1 + (size_t)n * 512;
    float acc = 0.f;
    for (int d = 0; d < 512; ++d) acc = fmaf(hr[d], ws2[d * 256 + c], acc);
    Y2[idx] = acc;
}

__global__ void s2_k(const float* __restrict__ Y2, float* __restrict__ S2) {
    int idx = blockIdx.x * 256 + threadIdx.x;
    if (idx >= T_EX * 256) return;
    int c = idx % 256, t = idx / 256;
    float acc = 0.f;
    for (int m = 0; m < MM; ++m) acc += Y2[(m * T_EX + t) * 256 + c];
    S2[idx] = acc;
}

__global__ void h2_k(const float* __restrict__ Y2, const float* __restrict__ S2,
                     const float* __restrict__ bs2, float* __restrict__ h2) {
    int idx = blockIdx.x * 256 + threadIdx.x;
    if (idx >= TM * 256) return;
    int c = idx % 256; int n = idx / 256;
    int t = n % T_EX;
    float val = S2[t * 256 + c] + bs2[c];
    if (t == 0) val -= Y2[idx];
    h2[idx] = lrelu(val);
}

__global__ void v1vx_k(const float* __restrict__ h2, const float* __restrict__ xhat,
                       float* __restrict__ V1, float* __restrict__ Vx) {
    int idx = blockIdx.x * 256 + threadIdx.x;
    if (idx >= DD * MM) return;
    int m = idx % MM, d = idx / MM;
    float mx = -INFINITY;
    for (int t = 0; t < T_EX; ++t) mx = fmaxf(mx, h2[(m * T_EX + t) * 256 + d]);
    V1[idx] = mx;
    Vx[idx] = mx + xhat[idx];
}

__global__ void lin88_k(const float* __restrict__ W, const float* __restrict__ bias,
                        const float* __restrict__ Vin, float* __restrict__ out) {
    int idx = blockIdx.x * 256 + threadIdx.x;
    if (idx >= DD * MM) return;
    int m = idx % MM, o = idx / MM;
    const float* wr = W + o * 256;
    float acc = bias[o];
    for (int i = 0; i < 256; ++i) acc = fmaf(wr[i], Vin[i * MM + m], acc);
    out[idx] = acc;
}

__global__ void smat_k(const float* __restrict__ Hh, const float* __restrict__ G,
                       float* __restrict__ Sm) {
    int idx = blockIdx.x * 256 + threadIdx.x;
    if (idx >= MM * MM) return;
    int i = idx % MM, j = idx / MM;
    float acc = 0.f;
    for (int c = 0; c < 256; ++c) acc = fmaf(Hh[c * MM + j], G[c * MM + i], acc);
    Sm[idx] = acc;
}

__global__ void softmax_k(const float* __restrict__ S, float* __restrict__ A2) {
    int j = blockIdx.x; int i = threadIdx.x;
    __shared__ float red[128];
    float val = (i < MM) ? S[j * MM + i] : -INFINITY;
    red[i] = val; __syncthreads();
    for (int s = 64; s > 0; s >>= 1) {
        if (i < s) red[i] = fmaxf(red[i], red[i + s]);
        __syncthreads();
    }
    float mx = red[0]; __syncthreads();
    float e = (i < MM) ? expf(val - mx) : 0.f;
    red[i] = e; __syncthreads();
    for (int s = 64; s > 0; s >>= 1) {
        if (i < s) red[i] += red[i + s];
        __syncthreads();
    }
    float inv = 1.f / red[0];
    if (i < MM) A2[j * MM + i] = e * inv;
}

__global__ void t1_k(const float* __restrict__ V1, const float* __restrict__ wc1,
                     float* __restrict__ t1) {
    int idx = blockIdx.x * 256 + threadIdx.x;
    if (idx >= MM * 384) return;
    int c = idx % 384, m = idx / 384;
    float acc = 0.f;
    for (int d = 0; d < 256; ++d) acc = fmaf(V1[d * MM + m], wc1[d * 384 + c], acc);
    t1[idx] = acc;
}

__global__ void c1_k(const float* __restrict__ A2, const float* __restrict__ t1,
                     const float* __restrict__ bc1, float* __restrict__ c1) {
    int idx = blockIdx.x * 256 + threadIdx.x;
    if (idx >= MM * 384) return;
    int c = idx % 384, j = idx / 384;
    float acc = bc1[c];
    for (int i = 0; i < MM; ++i) acc = fmaf(A2[j * MM + i], t1[i * 384 + c], acc);
    c1[idx] = lrelu(acc);
}

__global__ void t2_k(const float* __restrict__ c1, const float* __restrict__ wc2,
                     float* __restrict__ t2) {
    int idx = blockIdx.x * 256 + threadIdx.x;
    if (idx >= MM * 256) return;
    int c = idx % 256, m = idx / 256;
    const float* cr = c1 + m * 384;
    float acc = 0.f;
    for (int d = 0; d < 384; ++d) acc = fmaf(cr[d], wc2[d * 256 + c], acc);
    t2[idx] = acc;
}

__global__ void v2_k(const float* __restrict__ A2, const float* __restrict__ t2,
                     const float* __restrict__ bc2, float* __restrict__ V2m) {
    int idx = blockIdx.x * 256 + threadIdx.x;
    if (idx >= MM * 256) return;
    int c = idx % 256, j = idx / 256;
    float acc = bc2[c];
    for (int i = 0; i < MM; ++i) acc = fmaf(A2[j * MM + i], t2[i * 256 + c], acc);
    V2m[idx] = lrelu(acc);
}

__global__ void final_k(const float* __restrict__ Xf, const float* __restrict__ V2m,
                        float* __restrict__ out) {
    __shared__ float red[256];
    float acc = 0.f;
    for (int idx = threadIdx.x; idx < DD * MM; idx += 256) {
        int m = idx % MM, d = idx / MM;
        acc = fmaf(Xf[idx], V2m[m * 256 + d], acc);
    }
    red[threadIdx.x] = acc; __syncthreads();
    for (int s = 128; s > 0; s >>= 1) {
        if (threadIdx.x < s) red[threadIdx.x] += red[threadIdx.x + s];
        __syncthreads();
    }
    if (threadIdx.x == 0) out[0] = red[0];
}

extern "C" void kernel_launch(void* const* d_in, const int* in_sizes, int n_in,
                              void* d_out, int out_size, void* d_ws, size_t ws_size,
                              hipStream_t stream) {
    const float* search = (const float*)d_in[0];
    const float* exemp  = (const float*)d_in[1];
    const float* aw1 = (const float*)d_in[2];  const float* ab1 = (const float*)d_in[3];
    const float* aw2 = (const float*)d_in[4];  const float* ab2 = (const float*)d_in[5];
    const float* aw3 = (const float*)d_in[6];  const float* ab3 = (const float*)d_in[7];
    const float* aw4 = (const float*)d_in[8];  const float* ab4 = (const float*)d_in[9];
    const float* aw5 = (const float*)d_in[10]; const float* ab5 = (const float*)d_in[11];
    const float* wcd = (const float*)d_in[12]; const float* bcd = (const float*)d_in[13];
    const float* wt  = (const float*)d_in[14]; const float* bt  = (const float*)d_in[15];
    const float* ws1 = (const float*)d_in[16]; const float* bs1 = (const float*)d_in[17];
    const float* ws2 = (const float*)d_in[18]; const float* bs2 = (const float*)d_in[19];
    const float* wg  = (const float*)d_in[20]; const float* bg  = (const float*)d_in[21];
    const float* wh  = (const float*)d_in[22]; const float* bh  = (const float*)d_in[23];
    const float* wc1 = (const float*)d_in[24]; const float* bc1 = (const float*)d_in[25];
    const float* wc2 = (const float*)d_in[26]; const float* bc2 = (const float*)d_in[27];

    float* ws = (float*)d_ws;
    // ---- bf16 weight tiles (float-unit offsets) ----
    ushort_t* W1T = (ushort_t*)(ws + 0);        // 1*12*2048  = 24576 bf16
    ushort_t* W2T = (ushort_t*)(ws + 16384);    // 3*50*2048  = 307200
    ushort_t* W3T = (ushort_t*)(ws + 169984);   // 6*54*2048  = 663552
    ushort_t* W4T = (ushort_t*)(ws + 501760);   // 4*108*2048 = 884736
    ushort_t* W5T = (ushort_t*)(ws + 944128);   // 4*72*2048  = 589824
    // ---- bf16 activation ping/pong ----
    ushort_t* Au = (ushort_t*)(ws + 1245184);   // up to 7,338,560 bf16
    ushort_t* Bu = (ushort_t*)(ws + 4915200);   // up to 1,789,760 bf16
    float* P = ws + 5832704;                    // [17,256,88] fp32

    // ---- weight prep ----
    wprep_k<<<(3072 + 255) / 256, 256, 0, stream>>>(aw1, W1T, 363, 12, 3072);
    wprep_k<<<(38400 + 255) / 256, 256, 0, stream>>>(aw2, W2T, 1600, 50, 38400);
    wprep_k<<<(82944 + 255) / 256, 256, 0, stream>>>(aw3, W3T, 1728, 54, 82944);
    wprep_k<<<(110592 + 255) / 256, 256, 0, stream>>>(aw4, W4T, 3456, 108, 110592);
    wprep_k<<<(73728 + 255) / 256, 256, 0, stream>>>(aw5, W5T, 2304, 72, 73728);

    // ---- features (batch 17), MFMA convs ----
    conv_mfma<11, 11, 4, 2, true, true, true>
        <<<dim3((H1 * W1 + 63) / 64, 1, BATCH), 256, 0, stream>>>(
            search, exemp, W1T, ab1, Au, 3, H0, W0, H1, W1, 363, 12);
    {
        int total = BATCH * C1 * H1P * W1P;
        maxpool_bf<false><<<(total + 255) / 256, 256, 0, stream>>>(Au, Bu, C1, H1, W1, H1P, W1P);
    }
    conv_mfma<5, 5, 1, 2, false, false, false>
        <<<dim3((H1P * W1P + 63) / 64, C2 / 64, BATCH), 256, 0, stream>>>(
            Bu, nullptr, W2T, ab2, Au, 64, H1P, W1P, H1P, W1P, 1600, 50);
    {
        int total = BATCH * C2 * H2P * W2P;
        maxpool_bf<false><<<(total + 255) / 256, 256, 0, stream>>>(Au, Bu, C2, H1P, W1P, H2P, W2P);
    }
    conv_mfma<3, 3, 1, 1, false, false, false>
        <<<dim3((H2P * W2P + 63) / 64, C3 / 64, BATCH), 256, 0, stream>>>(
            Bu, nullptr, W3T, ab3, Au, 192, H2P, W2P, H2P, W2P, 1728, 54);
    conv_mfma<3, 3, 1, 1, false, false, false>
        <<<dim3((H2P * W2P + 63) / 64, C45 / 64, BATCH), 256, 0, stream>>>(
            Au, nullptr, W4T, ab4, Bu, 384, H2P, W2P, H2P, W2P, 3456, 108);
    conv_mfma<3, 3, 1, 1, false, false, false>
        <<<dim3((H2P * W2P + 63) / 64, C45 / 64, BATCH), 256, 0, stream>>>(
            Bu, nullptr, W5T, ab5, Au, 256, H2P, W2P, H2P, W2P, 2304, 72);
    {
        int total = BATCH * C45 * H5P * W5P;
        maxpool_bf<true><<<(total + 255) / 256, 256, 0, stream>>>(Au, P, C45, H2P, W2P, H5P, W5P);
    }

    float* Xf = P;

    // ---- tail buffers (fp32) ----
    float* v_   = ws + 6291456;
    float* xhat = ws + 6292480;
    float* Y1   = ws + 6315008;
    float* S1   = ws + 7035904;
    float* h1   = ws + 7044096;
    float* Y2   = ws + 7764992;
    float* S2   = ws + 8125440;
    float* h2   = ws + 8129536;
    float* V1   = ws + 8489984;
    float* Vx   = ws + 8512512;
    float* G    = ws + 8535040;
    float* Hh   = ws + 8557568;
    float* Sm   = ws + 8580096;
    float* A2   = ws + 8587840;
    float* t1   = ws + 8595584;
    float* c1   = ws + 8629376;
    float* t2   = ws + 8663168;
    float* V2m  = ws + 8685696;

    // conv_deconv branch
    cdv_k<<<256, 128, 0, stream>>>(Xf, wcd, bcd, v_);
    xhat_k<<<(DD * MM + 255) / 256, 256, 0, stream>>>(v_, wt, bt, xhat);

    // st GCN (A1 applied in structured form)
    y1_k<<<(TM * 512 + 255) / 256, 256, 0, stream>>>(P, ws1, Y1);
    s1_k<<<(T_EX * 512 + 255) / 256, 256, 0, stream>>>(Y1, S1);
    h1_k<<<(TM * 512 + 255) / 256, 256, 0, stream>>>(Y1, S1, bs1, h1);
    y2_k<<<(TM * 256 + 255) / 256, 256, 0, stream>>>(h1, ws2, Y2);
    s2_k<<<(T_EX * 256 + 255) / 256, 256, 0, stream>>>(Y2, S2);
    h2_k<<<(TM * 256 + 255) / 256, 256, 0, stream>>>(Y2, S2, bs2, h2);
    v1vx_k<<<(DD * MM + 255) / 256, 256, 0, stream>>>(h2, xhat, V1, Vx);

    // dynamic graph
    lin88_k<<<(DD * MM + 255) / 256, 256, 0, stream>>>(wg, bg, Vx, G);
    lin88_k<<<(DD * MM + 255) / 256, 256, 0, stream>>>(wh, bh, Vx, Hh);
    smat_k<<<(MM * MM + 255) / 256, 256, 0, stream>>>(Hh, G, Sm);
    softmax_k<<<MM, 128, 0, stream>>>(Sm, A2);

    // ct GCN
    t1_k<<<(MM * 384 + 255) / 256, 256, 0, stream>>>(V1, wc1, t1);
    c1_k<<<(MM * 384 + 255) / 256, 256, 0, stream>>>(A2, t1, bc1, c1);
    t2_k<<<(MM * 256 + 255) / 256, 256, 0, stream>>>(c1, wc2, t2);
    v2_k<<<(MM * 256 + 255) / 256, 256, 0, stream>>>(A2, t2, bc2, V2m);

    // final correlation -> scalar
    final_k<<<1, 256, 0, stream>>>(Xf, V2m, (float*)d_out);
}

// Round 4
// 754.743 us; speedup vs baseline: 12.8700x; 1.3430x over previous
//
#include <hip/hip_runtime.h>
#include <hip/hip_bf16.h>
#include <math.h>

// ---------- dims ----------
#define BATCH 17
#define T_EX 16
#define H0 383
#define W0 287
#define C1 64
#define H1 95
#define W1 71
#define H1P 47
#define W1P 35
#define C2 192
#define H2P 23
#define W2P 17
#define C3 384
#define C45 256
#define H5P 11
#define W5P 8
#define DD 256
#define MM 88
#define TM 1408

// conv1 padded input dims
#define HP1 389
#define WP1 292

typedef unsigned short ushort_t;
typedef unsigned int uint_t;
typedef __attribute__((ext_vector_type(8))) short short8;
typedef __attribute__((ext_vector_type(4))) float f32x4;

__device__ __forceinline__ float lrelu(float v) { return v > 0.f ? v : 0.01f * v; }

__device__ __forceinline__ ushort_t f2bf(float f) {
    unsigned int u = __float_as_uint(f);
    unsigned int r = (u + 0x7fffu + ((u >> 16) & 1u)) >> 16;
    return (ushort_t)r;
}
__device__ __forceinline__ float b2f(ushort_t b) {
    return __uint_as_float(((unsigned int)b) << 16);
}

// ---------- zero fill ----------
__global__ void zfill_k(float4* __restrict__ p, int n4) {
    int idx = blockIdx.x * 256 + threadIdx.x;
    if (idx < n4) p[idx] = (float4){0.f, 0.f, 0.f, 0.f};
}

// ---------- conv1 input prep: fp32 NCHW -> bf16 NHWC padded (C=4, pad y/x by 2) ----------
__global__ void prep1_k(const float* __restrict__ search, const float* __restrict__ exemp,
                        ushort_t* __restrict__ out) {
    int idx = blockIdx.x * 256 + threadIdx.x;
    if (idx >= BATCH * H0 * W0) return;
    int ix = idx % W0; int t = idx / W0;
    int iy = t % H0; int b = t / H0;
    const float* src = (b == 0) ? search : exemp + (size_t)(b - 1) * 3 * H0 * W0;
    const int hw = H0 * W0;
    float v0 = src[iy * W0 + ix];
    float v1 = src[hw + iy * W0 + ix];
    float v2 = src[2 * hw + iy * W0 + ix];
    ushort4 o;
    o.x = f2bf(v0); o.y = f2bf(v1); o.z = f2bf(v2); o.w = 0;
    *(ushort4*)&out[(((size_t)b * HP1 + iy + 2) * WP1 + ix + 2) * 4] = o;
}

// ---------- weight prep: OIHW fp32 -> bf16 MFMA tiles, K-order (ky,kx,ic) ----------
// tile chunk idx = ((ocb*NKS + ks)*256 + k8*64 + m), holds w[ocb*64+m][ks*32+k8*8+j]
__global__ void wprep_k(const float* __restrict__ w, ushort_t* __restrict__ out,
                        int KH, int KWl, int KWr, int CINl, int CINr,
                        int NKS, int nch) {
    int idx = blockIdx.x * 256 + threadIdx.x;
    if (idx >= nch) return;
    int c = idx & 255;
    int rest = idx >> 8;
    int ks = rest % NKS;
    int ocb = rest / NKS;
    int k8 = c >> 6, m = c & 63;
    int oc = ocb * 64 + m;
    int KWC = KWl * CINl;
    ushort_t* o = out + (size_t)idx * 8;
#pragma unroll
    for (int j = 0; j < 8; ++j) {
        int kg = ks * 32 + k8 * 8 + j;
        int ky = kg / KWC; int rem = kg - ky * KWC;
        int kx = rem / CINl; int ic = rem - kx * CINl;
        float v = 0.f;
        if (ky < KH && kx < KWr && ic < CINr)
            v = w[(((size_t)oc * CINr + ic) * KH + ky) * KWr + kx];
        o[j] = f2bf(v);
    }
}

// ====================================================================
// bf16 MFMA implicit-GEMM conv, NHWC padded input, table-driven gather.
// BM=64 oc x BN=64 spatial x BK=32; 4 waves, 4 MFMAs/wave/step.
// ====================================================================
template <int STRIDE, bool A16>
__global__ __launch_bounds__(256) void conv_mfma2(
    const ushort_t* __restrict__ inp, const ushort_t* __restrict__ wt,
    const float* __restrict__ bias, ushort_t* __restrict__ out,
    int Hp, int Wp, int C, int Wout, int HW, int NKS, int KWl,
    int OHp, int OWp, int OPAD, int COUT) {
    const int tid = threadIdx.x;
    const int wv = tid >> 6, lane = tid & 63;
    const int n_blk = blockIdx.x * 64;
    const int ocb = blockIdx.y;
    const int b = blockIdx.z;

    __shared__ ushort_t As[2048];
    __shared__ ushort_t Bs[2048];
    __shared__ int offs[448];

    const int KWC = KWl * C;
    for (int g = tid; g < NKS * 4; g += 256) {
        int kg = g * 8;
        int ky = kg / KWC; int rem = kg - ky * KWC;
        int kx = rem / C; int c8 = rem - kx * C;
        offs[g] = (ky * Wp + kx) * C + c8;
    }

    const ushort_t* inb = inp + (size_t)b * Hp * Wp * C;
    int n_g = n_blk + lane;
    int n_gc = n_g < HW ? n_g : HW - 1;          // clamp: no OOB ever
    int oy = n_gc / Wout, ox = n_gc - oy * Wout;
    const int base0 = (oy * STRIDE * Wp + ox * STRIDE) * C;

    f32x4 acc[4];
#pragma unroll
    for (int cn = 0; cn < 4; ++cn) acc[cn] = (f32x4){0.f, 0.f, 0.f, 0.f};

    const ushort_t* wblk = wt + (size_t)ocb * NKS * 2048;
    __syncthreads();   // offs table ready

    for (int ks = 0; ks < NKS; ++ks) {
        const short8 aval = *(const short8*)(wblk + ks * 2048 + tid * 8);
        const int off = offs[ks * 4 + wv];
        const ushort_t* src = inb + base0 + off;
        short8 bval;
        if (A16) {
            bval = *(const short8*)src;
        } else {
            union { uint2 u[2]; short8 s; } uu;
            uu.u[0] = *(const uint2*)src;
            uu.u[1] = *(const uint2*)(src + 4);
            bval = uu.s;
        }
        *(short8*)&As[tid * 8] = aval;
        *(short8*)&Bs[tid * 8] = bval;
        __syncthreads();
        {
            const int quad = lane >> 4, l16 = lane & 15;
            const short8 af = *(const short8*)&As[(quad * 64 + wv * 16 + l16) * 8];
#pragma unroll
            for (int cn = 0; cn < 4; ++cn) {
                const short8 bfr = *(const short8*)&Bs[(quad * 64 + cn * 16 + l16) * 8];
                acc[cn] = __builtin_amdgcn_mfma_f32_16x16x32_bf16(af, bfr, acc[cn], 0, 0, 0);
            }
        }
        __syncthreads();
    }

    // epilogue: bias + relu + packed bf16x4 store, NHWC (optionally padded interior)
    const int quad = lane >> 4, l16 = lane & 15;
    const int oc0 = ocb * 64 + wv * 16 + quad * 4;
    const float b0 = bias[oc0], b1 = bias[oc0 + 1], b2 = bias[oc0 + 2], b3 = bias[oc0 + 3];
#pragma unroll
    for (int cn = 0; cn < 4; ++cn) {
        int n = n_blk + cn * 16 + l16;
        if (n < HW) {
            int y = n / Wout, x = n - y * Wout;
            size_t base = (((size_t)b * OHp + y + OPAD) * OWp + x + OPAD) * COUT + oc0;
            ushort4 o;
            o.x = f2bf(fmaxf(acc[cn][0] + b0, 0.f));
            o.y = f2bf(fmaxf(acc[cn][1] + b1, 0.f));
            o.z = f2bf(fmaxf(acc[cn][2] + b2, 0.f));
            o.w = f2bf(fmaxf(acc[cn][3] + b3, 0.f));
            *(ushort4*)&out[base] = o;
        }
    }
}

// ---------- maxpool k3 s2 VALID, NHWC; optional fp32 out, optional out pad ----------
template <bool OUTF32>
__global__ void pool_nhwc(const ushort_t* __restrict__ in, void* __restrict__ outv,
                          int C, int Hin, int Win, int Hout, int Wout,
                          int OHp, int OWp, int OPAD) {
    int total = BATCH * C * Hout * Wout;
    int idx = blockIdx.x * 256 + threadIdx.x;
    if (idx >= total) return;
    int c = idx % C; int r = idx / C;
    int x = r % Wout; r /= Wout;
    int y = r % Hout; int b = r / Hout;
    const int rs = Win * C;
    const ushort_t* p = in + (((size_t)b * Hin + 2 * y) * Win + 2 * x) * C + c;
    float m = b2f(p[0]);
    m = fmaxf(m, b2f(p[C])); m = fmaxf(m, b2f(p[2 * C]));
    m = fmaxf(m, b2f(p[rs])); m = fmaxf(m, b2f(p[rs + C])); m = fmaxf(m, b2f(p[rs + 2 * C]));
    m = fmaxf(m, b2f(p[2 * rs])); m = fmaxf(m, b2f(p[2 * rs + C])); m = fmaxf(m, b2f(p[2 * rs + 2 * C]));
    size_t oaddr = (((size_t)b * OHp + y + OPAD) * OWp + x + OPAD) * C + c;
    if (OUTF32) ((float*)outv)[oaddr] = m;
    else        ((ushort_t*)outv)[oaddr] = f2bf(m);
}

// ---------- conv_deconv: conv1d(k3,p1) over positions + global max -> v[256] ----------
// Xf2 layout: [m][i] (P is [b][m][d])
__global__ void cdv_k(const float* __restrict__ Xf2, const float* __restrict__ wcd,
                      const float* __restrict__ bcd, float* __restrict__ v) {
    int c = blockIdx.x;
    int m = threadIdx.x;
    float val = -INFINITY;
    if (m < MM) {
        float acc = bcd[c];
        const float* wrow = wcd + c * 256 * 3;
        const float* rm = Xf2 + (size_t)m * 256;
        for (int i = 0; i < 256; ++i) {
            float w0 = wrow[i * 3 + 0], w1 = wrow[i * 3 + 1], w2 = wrow[i * 3 + 2];
            if (m > 0) acc = fmaf(w0, rm[i - 256], acc);
            acc = fmaf(w1, rm[i], acc);
            if (m < MM - 1) acc = fmaf(w2, rm[i + 256], acc);
        }
        val = acc;
    }
    __shared__ float red[128];
    red[threadIdx.x] = val;
    __syncthreads();
    for (int s = 64; s > 0; s >>= 1) {
        if (threadIdx.x < s) red[threadIdx.x] = fmaxf(red[threadIdx.x], red[threadIdx.x + s]);
        __syncthreads();
    }
    if (threadIdx.x == 0) v[c] = red[0];
}

__global__ void xhat_k(const float* __restrict__ v, const float* __restrict__ wt,
                       const float* __restrict__ bt, float* __restrict__ xhat) {
    __shared__ float lv[256];
    for (int j = threadIdx.x; j < 256; j += 256) lv[j] = v[j];
    __syncthreads();
    int idx = blockIdx.x * 256 + threadIdx.x;
    if (idx >= DD * MM) return;
    int k = idx % MM, o = idx / MM;
    float acc = bt[o];
    for (int i = 0; i < 256; ++i) acc = fmaf(lv[i], wt[(i * 256 + o) * MM + k], acc);
    xhat[idx] = acc;
}

// ---------- Y1 = nodes @ ws1 ; node n=t+16m -> P[(1+t)][m][:] (contiguous) ----------
__global__ void y1_k(const float* __restrict__ P, const float* __restrict__ ws1,
                     float* __restrict__ Y1) {
    int idx = blockIdx.x * 256 + threadIdx.x;
    if (idx >= TM * 512) return;
    int c = idx % 512; int n = idx / 512;
    int t = n % T_EX, m = n / T_EX;
    const float* node = P + ((size_t)(1 + t) * MM + m) * 256;
    float acc = 0.f;
    for (int d = 0; d < 256; ++d) acc = fmaf(node[d], ws1[d * 512 + c], acc);
    Y1[idx] = acc;
}

__global__ void s1_k(const float* __restrict__ Y1, float* __restrict__ S1) {
    int idx = blockIdx.x * 256 + threadIdx.x;
    if (idx >= T_EX * 512) return;
    int c = idx % 512, t = idx / 512;
    float acc = 0.f;
    for (int m = 0; m < MM; ++m) acc += Y1[(m * T_EX + t) * 512 + c];
    S1[idx] = acc;
}

__global__ void h1_k(const float* __restrict__ Y1, const float* __restrict__ S1,
                     const float* __restrict__ bs1, float* __restrict__ h1) {
    int idx = blockIdx.x * 256 + threadIdx.x;
    if (idx >= TM * 512) return;
    int c = idx % 512; int n = idx / 512;
    int t = n % T_EX;
    float val = S1[t * 512 + c] + bs1[c];
    if (t == 0) val -= Y1[idx];
    h1[idx] = lrelu(val);
}

__global__ void y2_k(const float* __restrict__ h1, const float* __restrict__ ws2,
                     float* __restrict__ Y2) {
    int idx = blockIdx.x * 256 + threadIdx.x;
    if (idx >= TM * 256) return;
    int c = idx % 256; int n = idx / 256;
    const float* hr = h1 + (size_t)n * 512;
    float acc = 0.f;
    for (int d = 0; d < 512; ++d) acc = fmaf(hr[d], ws2[d * 256 + c], acc);
    Y2[idx] = acc;
}

__global__ void s2_k(const float* __restrict__ Y2, float* __restrict__ S2) {
    int idx = blockIdx.x * 256 + threadIdx.x;
    if (idx >= T_EX * 256) return;
    int c = idx % 256, t = idx / 256;
    float acc = 0.f;
    for (int m = 0; m < MM; ++m) acc += Y2[(m * T_EX + t) * 256 + c];
    S2[idx] = acc;
}

__global__ void h2_k(const float* __restrict__ Y2, const float* __restrict__ S2,
                     const float* __restrict__ bs2, float* __restrict__ h2) {
    int idx = blockIdx.x * 256 + threadIdx.x;
    if (idx >= TM * 256) return;
    int c = idx % 256; int n = idx / 256;
    int t = n % T_EX;
    float val = S2[t * 256 + c] + bs2[c];
    if (t == 0) val -= Y2[idx];
    h2[idx] = lrelu(val);
}

__global__ void v1vx_k(const float* __restrict__ h2, const float* __restrict__ xhat,
                       float* __restrict__ V1, float* __restrict__ Vx) {
    int idx = blockIdx.x * 256 + threadIdx.x;
    if (idx >= DD * MM) return;
    int m = idx % MM, d = idx / MM;
    float mx = -INFINITY;
    for (int t = 0; t < T_EX; ++t) mx = fmaxf(mx, h2[(m * T_EX + t) * 256 + d]);
    V1[idx] = mx;
    Vx[idx] = mx + xhat[idx];
}

__global__ void lin88_k(const float* __restrict__ W, const float* __restrict__ bias,
                        const float* __restrict__ Vin, float* __restrict__ out) {
    int idx = blockIdx.x * 256 + threadIdx.x;
    if (idx >= DD * MM) return;
    int m = idx % MM, o = idx / MM;
    const float* wr = W + o * 256;
    float acc = bias[o];
    for (int i = 0; i < 256; ++i) acc = fmaf(wr[i], Vin[i * MM + m], acc);
    out[idx] = acc;
}

__global__ void smat_k(const float* __restrict__ Hh, const float* __restrict__ G,
                       float* __restrict__ Sm) {
    int idx = blockIdx.x * 256 + threadIdx.x;
    if (idx >= MM * MM) return;
    int i = idx % MM, j = idx / MM;
    float acc = 0.f;
    for (int c = 0; c < 256; ++c) acc = fmaf(Hh[c * MM + j], G[c * MM + i], acc);
    Sm[idx] = acc;
}

__global__ void softmax_k(const float* __restrict__ S, float* __restrict__ A2) {
    int j = blockIdx.x; int i = threadIdx.x;
    __shared__ float red[128];
    float val = (i < MM) ? S[j * MM + i] : -INFINITY;
    red[i] = val; __syncthreads();
    for (int s = 64; s > 0; s >>= 1) {
        if (i < s) red[i] = fmaxf(red[i], red[i + s]);
        __syncthreads();
    }
    float mx = red[0]; __syncthreads();
    float e = (i < MM) ? expf(val - mx) : 0.f;
    red[i] = e; __syncthreads();
    for (int s = 64; s > 0; s >>= 1) {
        if (i < s) red[i] += red[i + s];
        __syncthreads();
    }
    float inv = 1.f / red[0];
    if (i < MM) A2[j * MM + i] = e * inv;
}

__global__ void t1_k(const float* __restrict__ V1, const float* __restrict__ wc1,
                     float* __restrict__ t1) {
    int idx = blockIdx.x * 256 + threadIdx.x;
    if (idx >= MM * 384) return;
    int c = idx % 384, m = idx / 384;
    float acc = 0.f;
    for (int d = 0; d < 256; ++d) acc = fmaf(V1[d * MM + m], wc1[d * 384 + c], acc);
    t1[idx] = acc;
}

__global__ void c1_k(const float* __restrict__ A2, const float* __restrict__ t1,
                     const float* __restrict__ bc1, float* __restrict__ c1) {
    int idx = blockIdx.x * 256 + threadIdx.x;
    if (idx >= MM * 384) return;
    int c = idx % 384, j = idx / 384;
    float acc = bc1[c];
    for (int i = 0; i < MM; ++i) acc = fmaf(A2[j * MM + i], t1[i * 384 + c], acc);
    c1[idx] = lrelu(acc);
}

__global__ void t2_k(const float* __restrict__ c1, const float* __restrict__ wc2,
                     float* __restrict__ t2) {
    int idx = blockIdx.x * 256 + threadIdx.x;
    if (idx >= MM * 256) return;
    int c = idx % 256, m = idx / 256;
    const float* cr = c1 + m * 384;
    float acc = 0.f;
    for (int d = 0; d < 384; ++d) acc = fmaf(cr[d], wc2[d * 256 + c], acc);
    t2[idx] = acc;
}

__global__ void v2_k(const float* __restrict__ A2, const float* __restrict__ t2,
                     const float* __restrict__ bc2, float* __restrict__ V2m) {
    int idx = blockIdx.x * 256 + threadIdx.x;
    if (idx >= MM * 256) return;
    int c = idx % 256, j = idx / 256;
    float acc = bc2[c];
    for (int i = 0; i < MM; ++i) acc = fmaf(A2[j * MM + i], t2[i * 256 + c], acc);
    V2m[idx] = lrelu(acc);
}

// ---------- R = sum Xf2[m][d] * V2m[m][d] (both [m][d]) ----------
__global__ void final_k(const float* __restrict__ Xf2, const float* __restrict__ V2m,
                        float* __restrict__ out) {
    __shared__ float red[256];
    float acc = 0.f;
    for (int idx = threadIdx.x; idx < DD * MM; idx += 256)
        acc = fmaf(Xf2[idx], V2m[idx], acc);
    red[threadIdx.x] = acc; __syncthreads();
    for (int s = 128; s > 0; s >>= 1) {
        if (threadIdx.x < s) red[threadIdx.x] += red[threadIdx.x + s];
        __syncthreads();
    }
    if (threadIdx.x == 0) out[0] = red[0];
}

extern "C" void kernel_launch(void* const* d_in, const int* in_sizes, int n_in,
                              void* d_out, int out_size, void* d_ws, size_t ws_size,
                              hipStream_t stream) {
    const float* search = (const float*)d_in[0];
    const float* exemp  = (const float*)d_in[1];
    const float* aw1 = (const float*)d_in[2];  const float* ab1 = (const float*)d_in[3];
    const float* aw2 = (const float*)d_in[4];  const float* ab2 = (const float*)d_in[5];
    const float* aw3 = (const float*)d_in[6];  const float* ab3 = (const float*)d_in[7];
    const float* aw4 = (const float*)d_in[8];  const float* ab4 = (const float*)d_in[9];
    const float* aw5 = (const float*)d_in[10]; const float* ab5 = (const float*)d_in[11];
    const float* wcd = (const float*)d_in[12]; const float* bcd = (const float*)d_in[13];
    const float* wt  = (const float*)d_in[14]; const float* bt  = (const float*)d_in[15];
    const float* ws1 = (const float*)d_in[16]; const float* bs1 = (const float*)d_in[17];
    const float* ws2 = (const float*)d_in[18]; const float* bs2 = (const float*)d_in[19];
    const float* wg  = (const float*)d_in[20]; const float* bg  = (const float*)d_in[21];
    const float* wh  = (const float*)d_in[22]; const float* bh  = (const float*)d_in[23];
    const float* wc1 = (const float*)d_in[24]; const float* bc1 = (const float*)d_in[25];
    const float* wc2 = (const float*)d_in[26]; const float* bc2 = (const float*)d_in[27];

    float* ws = (float*)d_ws;
    // ---- regions (float units), lifetime-aliased; total 9.07M floats = 36.3 MB ----
    // R1 [0, 3870720): in1p -> c2out -> c4out -> tail+P
    // R2 [3870720, 7544832): c1out -> (p2out | c3out @ +775200)
    // R3 [7544832, 8628864): p1out -> c5out
    // Wg [8628864, 9071616): shared weight-tile region (rewritten per conv)
    float* R1 = ws;
    float* R2 = ws + 3870720;
    float* R3 = ws + 7544832;
    float* Wg = ws + 8628864;

    ushort_t* in1p  = (ushort_t*)R1;               // [17][389][292][4]
    ushort_t* c1out = (ushort_t*)R2;               // [17][95][71][64]
    ushort_t* p1out = (ushort_t*)R3;               // [17][51][39][64] padded
    ushort_t* c2out = (ushort_t*)R1;               // [17][47][35][192]
    ushort_t* p2out = (ushort_t*)R2;               // [17][25][19][192] padded
    ushort_t* c3out = (ushort_t*)(R2 + 775200);    // [17][25][19][384] padded
    ushort_t* c4out = (ushort_t*)R1;               // [17][25][19][256] padded
    ushort_t* c5out = (ushort_t*)R3;               // [17][23][17][256]
    ushort_t* WT    = (ushort_t*)Wg;

    // ---- conv1 ----
    zfill_k<<<(965500 + 255) / 256, 256, 0, stream>>>((float4*)R1, 965500);   // in1p zeros
    prep1_k<<<(BATCH * H0 * W0 + 255) / 256, 256, 0, stream>>>(search, exemp, in1p);
    wprep_k<<<(4352 + 255) / 256, 256, 0, stream>>>(aw1, WT, 11, 12, 11, 4, 3, 17, 4352);
    conv_mfma2<4, false><<<dim3(106, 1, BATCH), 256, 0, stream>>>(
        in1p, WT, ab1, c1out, HP1, WP1, 4, W1, H1 * W1, 17, 12, H1, W1, 0, 64);
    // ---- pool1 (padded out for conv2) ----
    zfill_k<<<(270504 + 255) / 256, 256, 0, stream>>>((float4*)R3, 270504);
    pool_nhwc<false><<<(BATCH * 64 * H1P * W1P + 255) / 256, 256, 0, stream>>>(
        c1out, p1out, 64, H1, W1, H1P, W1P, 51, 39, 2);
    // ---- conv2 ----
    wprep_k<<<(38400 + 255) / 256, 256, 0, stream>>>(aw2, WT, 5, 5, 5, 64, 64, 50, 38400);
    conv_mfma2<1, true><<<dim3(26, 3, BATCH), 256, 0, stream>>>(
        p1out, WT, ab2, c2out, 51, 39, 64, W1P, H1P * W1P, 50, 5, H1P, W1P, 0, 192);
    // ---- pool2 (padded out) + conv3 out pads: zero R2[0, 2325600) ----
    zfill_k<<<(581400 + 255) / 256, 256, 0, stream>>>((float4*)R2, 581400);
    pool_nhwc<false><<<(BATCH * 192 * H2P * W2P + 255) / 256, 256, 0, stream>>>(
        c2out, p2out, 192, H1P, W1P, H2P, W2P, 25, 19, 1);
    // ---- conv3 (writes padded interior of c3out) ----
    wprep_k<<<(82944 + 255) / 256, 256, 0, stream>>>(aw3, WT, 3, 3, 3, 192, 192, 54, 82944);
    conv_mfma2<1, true><<<dim3(7, 6, BATCH), 256, 0, stream>>>(
        p2out, WT, ab3, c3out, 25, 19, 192, W2P, H2P * W2P, 54, 3, 25, 19, 1, 384);
    // ---- conv4 (zero c4out pads in R1; c2out dead) ----
    zfill_k<<<(258400 + 255) / 256, 256, 0, stream>>>((float4*)R1, 258400);
    wprep_k<<<(110592 + 255) / 256, 256, 0, stream>>>(aw4, WT, 3, 3, 3, 384, 384, 108, 110592);
    conv_mfma2<1, true><<<dim3(7, 4, BATCH), 256, 0, stream>>>(
        c3out, WT, ab4, c4out, 25, 19, 384, W2P, H2P * W2P, 108, 3, 25, 19, 1, 256);
    // ---- conv5 (unpadded out) ----
    wprep_k<<<(73728 + 255) / 256, 256, 0, stream>>>(aw5, WT, 3, 3, 3, 256, 256, 72, 73728);
    conv_mfma2<1, true><<<dim3(7, 4, BATCH), 256, 0, stream>>>(
        c4out, WT, ab5, c5out, 25, 19, 256, W2P, H2P * W2P, 72, 3, H2P, W2P, 0, 256);

    // ---- pool5 -> P fp32 [b][m][d] ----
    float* P = R1 + 2417664;
    pool_nhwc<true><<<(BATCH * 256 * H5P * W5P + 255) / 256, 256, 0, stream>>>(
        c5out, P, 256, H2P, W2P, H5P, W5P, H5P, W5P, 0);
    float* Xf2 = P;   // [m][d] for b=0

    // ---- tail buffers in R1 (convs done; P lives above them) ----
    float* v_   = R1 + 0;
    float* xhat = R1 + 1024;
    float* Y1   = R1 + 23552;
    float* S1   = R1 + 744448;
    float* h1   = R1 + 752640;
    float* Y2   = R1 + 1473536;
    float* S2   = R1 + 1833984;
    float* h2   = R1 + 1838080;
    float* V1   = R1 + 2198528;
    float* Vx   = R1 + 2221056;
    float* G    = R1 + 2243584;
    float* Hh   = R1 + 2266112;
    float* Sm   = R1 + 2288640;
    float* A2   = R1 + 2296832;
    float* t1   = R1 + 2305024;
    float* c1   = R1 + 2338816;
    float* t2   = R1 + 2372608;
    float* V2m  = R1 + 2395136;

    // conv_deconv branch
    cdv_k<<<256, 128, 0, stream>>>(Xf2, wcd, bcd, v_);
    xhat_k<<<(DD * MM + 255) / 256, 256, 0, stream>>>(v_, wt, bt, xhat);

    // st GCN (A1 structured)
    y1_k<<<(TM * 512 + 255) / 256, 256, 0, stream>>>(P, ws1, Y1);
    s1_k<<<(T_EX * 512 + 255) / 256, 256, 0, stream>>>(Y1, S1);
    h1_k<<<(TM * 512 + 255) / 256, 256, 0, stream>>>(Y1, S1, bs1, h1);
    y2_k<<<(TM * 256 + 255) / 256, 256, 0, stream>>>(h1, ws2, Y2);
    s2_k<<<(T_EX * 256 + 255) / 256, 256, 0, stream>>>(Y2, S2);
    h2_k<<<(TM * 256 + 255) / 256, 256, 0, stream>>>(Y2, S2, bs2, h2);
    v1vx_k<<<(DD * MM + 255) / 256, 256, 0, stream>>>(h2, xhat, V1, Vx);

    // dynamic graph
    lin88_k<<<(DD * MM + 255) / 256, 256, 0, stream>>>(wg, bg, Vx, G);
    lin88_k<<<(DD * MM + 255) / 256, 256, 0, stream>>>(wh, bh, Vx, Hh);
    smat_k<<<(MM * MM + 255) / 256, 256, 0, stream>>>(Hh, G, Sm);
    softmax_k<<<MM, 128, 0, stream>>>(Sm, A2);

    // ct GCN
    t1_k<<<(MM * 384 + 255) / 256, 256, 0, stream>>>(V1, wc1, t1);
    c1_k<<<(MM * 384 + 255) / 256, 256, 0, stream>>>(A2, t1, bc1, c1);
    t2_k<<<(MM * 256 + 255) / 256, 256, 0, stream>>>(c1, wc2, t2);
    v2_k<<<(MM * 256 + 255) / 256, 256, 0, stream>>>(A2, t2, bc2, V2m);

    final_k<<<1, 256, 0, stream>>>(Xf2, V2m, (float*)d_out);
}

// Round 5
// 618.062 us; speedup vs baseline: 15.7162x; 1.2211x over previous
//
#include <hip/hip_runtime.h>
#include <hip/hip_bf16.h>
#include <math.h>

// ---------- dims ----------
#define BATCH 17
#define T_EX 16
#define H0 383
#define W0 287
#define C1 64
#define H1 95
#define W1 71
#define H1P 47
#define W1P 35
#define C2 192
#define H2P 23
#define W2P 17
#define C3 384
#define C45 256
#define H5P 11
#define W5P 8
#define DD 256
#define MM 88
#define TM 1408

#define HP1 389
#define WP1 292

typedef unsigned short ushort_t;
typedef __attribute__((ext_vector_type(8))) short short8;
typedef __attribute__((ext_vector_type(4))) float f32x4;

__device__ __forceinline__ float lrelu(float v) { return v > 0.f ? v : 0.01f * v; }

__device__ __forceinline__ ushort_t f2bf(float f) {
    unsigned int u = __float_as_uint(f);
    unsigned int r = (u + 0x7fffu + ((u >> 16) & 1u)) >> 16;
    return (ushort_t)r;
}
__device__ __forceinline__ float b2f(ushort_t b) {
    return __uint_as_float(((unsigned int)b) << 16);
}

// ---------- zero fill ----------
__global__ void zfill_k(float4* __restrict__ p, int n4) {
    int idx = blockIdx.x * 256 + threadIdx.x;
    if (idx < n4) p[idx] = (float4){0.f, 0.f, 0.f, 0.f};
}

// ---------- conv1 input prep: fp32 NCHW -> bf16 NHWC padded (C=4, pad 2) ----------
__global__ void prep1_k(const float* __restrict__ search, const float* __restrict__ exemp,
                        ushort_t* __restrict__ out) {
    int idx = blockIdx.x * 256 + threadIdx.x;
    if (idx >= BATCH * H0 * W0) return;
    int ix = idx % W0; int t = idx / W0;
    int iy = t % H0; int b = t / H0;
    const float* src = (b == 0) ? search : exemp + (size_t)(b - 1) * 3 * H0 * W0;
    const int hw = H0 * W0;
    float v0 = src[iy * W0 + ix];
    float v1 = src[hw + iy * W0 + ix];
    float v2 = src[2 * hw + iy * W0 + ix];
    ushort4 o;
    o.x = f2bf(v0); o.y = f2bf(v1); o.z = f2bf(v2); o.w = 0;
    *(ushort4*)&out[(((size_t)b * HP1 + iy + 2) * WP1 + ix + 2) * 4] = o;
}

// ---------- conv weight prep: OIHW fp32 -> bf16 MFMA tiles, K-order (ky,kx,ic) ----------
__global__ void wprep_k(const float* __restrict__ w, ushort_t* __restrict__ out,
                        int KH, int KWl, int KWr, int CINl, int CINr,
                        int NKS, int nch) {
    int idx = blockIdx.x * 256 + threadIdx.x;
    if (idx >= nch) return;
    int c = idx & 255;
    int rest = idx >> 8;
    int ks = rest % NKS;
    int ocb = rest / NKS;
    int k8 = c >> 6, m = c & 63;
    int oc = ocb * 64 + m;
    int KWC = KWl * CINl;
    ushort_t* o = out + (size_t)idx * 8;
#pragma unroll
    for (int j = 0; j < 8; ++j) {
        int kg = ks * 32 + k8 * 8 + j;
        int ky = kg / KWC; int rem = kg - ky * KWC;
        int kx = rem / CINl; int ic = rem - kx * CINl;
        float v = 0.f;
        if (ky < KH && kx < KWr && ic < CINr)
            v = w[(((size_t)oc * CINr + ic) * KH + ky) * KWr + kx];
        o[j] = f2bf(v);
    }
}

// ---------- generic GEMM weight prep ----------
// MODE 0: A[oc][kg] = src[oc*sa + kg*sk]  (transposed linear gather)
// MODE 1 (cdv): A[c][kg=dk*256+i] = src[c*768 + i*3 + dk]
template <int MODE>
__global__ void wprep2_k(const float* __restrict__ src, ushort_t* __restrict__ out,
                         int sa, int sk, int NKS, int nch) {
    int idx = blockIdx.x * 256 + threadIdx.x;
    if (idx >= nch) return;
    int c = idx & 255;
    int rest = idx >> 8;
    int ks = rest % NKS;
    int ocb = rest / NKS;
    int k8 = c >> 6, m = c & 63;
    int oc = ocb * 64 + m;
    ushort_t* o = out + (size_t)idx * 8;
#pragma unroll
    for (int j = 0; j < 8; ++j) {
        int kg = ks * 32 + k8 * 8 + j;
        float v;
        if (MODE == 0) v = src[(size_t)oc * sa + (size_t)kg * sk];
        else           v = src[(size_t)oc * 768 + (kg & 255) * 3 + (kg >> 8)];
        o[j] = f2bf(v);
    }
}

// ====================================================================
// bf16 MFMA implicit-GEMM conv, NHWC padded input, table-driven gather.
// ====================================================================
template <int STRIDE, bool A16>
__global__ __launch_bounds__(256) void conv_mfma2(
    const ushort_t* __restrict__ inp, const ushort_t* __restrict__ wt,
    const float* __restrict__ bias, ushort_t* __restrict__ out,
    int Hp, int Wp, int C, int Wout, int HW, int NKS, int KWl,
    int OHp, int OWp, int OPAD, int COUT) {
    const int tid = threadIdx.x;
    const int wv = tid >> 6, lane = tid & 63;
    const int n_blk = blockIdx.x * 64;
    const int ocb = blockIdx.y;
    const int b = blockIdx.z;

    __shared__ ushort_t As[2048];
    __shared__ ushort_t Bs[2048];
    __shared__ int offs[448];

    const int KWC = KWl * C;
    for (int g = tid; g < NKS * 4; g += 256) {
        int kg = g * 8;
        int ky = kg / KWC; int rem = kg - ky * KWC;
        int kx = rem / C; int c8 = rem - kx * C;
        offs[g] = (ky * Wp + kx) * C + c8;
    }

    const ushort_t* inb = inp + (size_t)b * Hp * Wp * C;
    int n_g = n_blk + lane;
    int n_gc = n_g < HW ? n_g : HW - 1;
    int oy = n_gc / Wout, ox = n_gc - oy * Wout;
    const int base0 = (oy * STRIDE * Wp + ox * STRIDE) * C;

    f32x4 acc[4];
#pragma unroll
    for (int cn = 0; cn < 4; ++cn) acc[cn] = (f32x4){0.f, 0.f, 0.f, 0.f};

    const ushort_t* wblk = wt + (size_t)ocb * NKS * 2048;
    __syncthreads();

    for (int ks = 0; ks < NKS; ++ks) {
        const short8 aval = *(const short8*)(wblk + ks * 2048 + tid * 8);
        const int off = offs[ks * 4 + wv];
        const ushort_t* src = inb + base0 + off;
        short8 bval;
        if (A16) {
            bval = *(const short8*)src;
        } else {
            union { uint2 u[2]; short8 s; } uu;
            uu.u[0] = *(const uint2*)src;
            uu.u[1] = *(const uint2*)(src + 4);
            bval = uu.s;
        }
        *(short8*)&As[tid * 8] = aval;
        *(short8*)&Bs[tid * 8] = bval;
        __syncthreads();
        {
            const int quad = lane >> 4, l16 = lane & 15;
            const short8 af = *(const short8*)&As[(quad * 64 + wv * 16 + l16) * 8];
#pragma unroll
            for (int cn = 0; cn < 4; ++cn) {
                const short8 bfr = *(const short8*)&Bs[(quad * 64 + cn * 16 + l16) * 8];
                acc[cn] = __builtin_amdgcn_mfma_f32_16x16x32_bf16(af, bfr, acc[cn], 0, 0, 0);
            }
        }
        __syncthreads();
    }

    const int quad = lane >> 4, l16 = lane & 15;
    const int oc0 = ocb * 64 + wv * 16 + quad * 4;
    const float b0 = bias[oc0], b1 = bias[oc0 + 1], b2 = bias[oc0 + 2], b3 = bias[oc0 + 3];
#pragma unroll
    for (int cn = 0; cn < 4; ++cn) {
        int n = n_blk + cn * 16 + l16;
        if (n < HW) {
            int y = n / Wout, x = n - y * Wout;
            size_t base = (((size_t)b * OHp + y + OPAD) * OWp + x + OPAD) * COUT + oc0;
            ushort4 o;
            o.x = f2bf(fmaxf(acc[cn][0] + b0, 0.f));
            o.y = f2bf(fmaxf(acc[cn][1] + b1, 0.f));
            o.z = f2bf(fmaxf(acc[cn][2] + b2, 0.f));
            o.w = f2bf(fmaxf(acc[cn][3] + b3, 0.f));
            *(ushort4*)&out[base] = o;
        }
    }
}

// ====================================================================
// Generic bf16 MFMA GEMM: out[oc][n] = sum_k A[oc][k]*B[k][n].
// B[k][n] = Bsrc[row(n)*RS + k]  (contiguous in k).
// MODE 0: row = n. MODE 1 (st-gcn nodes): row = (1+(n&15))*88 + (n>>4).
// Output fp32 at out[n*sn + oc*sc]; SC1 -> float4 store (sc==1).
// ====================================================================
template <int MODE, bool HASBIAS, bool SC1>
__global__ __launch_bounds__(256) void gemm_mfma(
    const ushort_t* __restrict__ Bsrc, const ushort_t* __restrict__ wt,
    const float* __restrict__ bias, float* __restrict__ out,
    int RS, int N, int NKS, int sn, int sc) {
    const int tid = threadIdx.x;
    const int wv = tid >> 6, lane = tid & 63;
    const int n_blk = blockIdx.x * 64;
    const int ocb = blockIdx.y;

    __shared__ ushort_t As[2048];
    __shared__ ushort_t Bs[2048];

    int n_g = n_blk + lane;
    int n_gc = n_g < N ? n_g : N - 1;
    int row = (MODE == 1) ? (1 + (n_gc & 15)) * MM + (n_gc >> 4) : n_gc;
    const size_t base0 = (size_t)row * RS;

    f32x4 acc[4];
#pragma unroll
    for (int cn = 0; cn < 4; ++cn) acc[cn] = (f32x4){0.f, 0.f, 0.f, 0.f};

    const ushort_t* wblk = wt + (size_t)ocb * NKS * 2048;

    for (int ks = 0; ks < NKS; ++ks) {
        const short8 aval = *(const short8*)(wblk + ks * 2048 + tid * 8);
        const short8 bval = *(const short8*)(Bsrc + base0 + ks * 32 + wv * 8);
        *(short8*)&As[tid * 8] = aval;
        *(short8*)&Bs[tid * 8] = bval;
        __syncthreads();
        {
            const int quad = lane >> 4, l16 = lane & 15;
            const short8 af = *(const short8*)&As[(quad * 64 + wv * 16 + l16) * 8];
#pragma unroll
            for (int cn = 0; cn < 4; ++cn) {
                const short8 bfr = *(const short8*)&Bs[(quad * 64 + cn * 16 + l16) * 8];
                acc[cn] = __builtin_amdgcn_mfma_f32_16x16x32_bf16(af, bfr, acc[cn], 0, 0, 0);
            }
        }
        __syncthreads();
    }

    const int quad = lane >> 4, l16 = lane & 15;
    const int oc0 = ocb * 64 + wv * 16 + quad * 4;
    float bb[4] = {0.f, 0.f, 0.f, 0.f};
    if (HASBIAS) { bb[0] = bias[oc0]; bb[1] = bias[oc0+1]; bb[2] = bias[oc0+2]; bb[3] = bias[oc0+3]; }
#pragma unroll
    for (int cn = 0; cn < 4; ++cn) {
        int n = n_blk + cn * 16 + l16;
        if (n < N) {
            if (SC1) {
                float4 o;
                o.x = acc[cn][0] + bb[0]; o.y = acc[cn][1] + bb[1];
                o.z = acc[cn][2] + bb[2]; o.w = acc[cn][3] + bb[3];
                *(float4*)&out[(size_t)n * sn + oc0] = o;
            } else {
#pragma unroll
                for (int reg = 0; reg < 4; ++reg)
                    out[(size_t)n * sn + (size_t)(oc0 + reg) * sc] = acc[cn][reg] + bb[reg];
            }
        }
    }
}

// ---------- maxpool k3 s2 VALID, NHWC bf16 ----------
__global__ void pool_nhwc(const ushort_t* __restrict__ in, ushort_t* __restrict__ out,
                          int C, int Hin, int Win, int Hout, int Wout,
                          int OHp, int OWp, int OPAD) {
    int total = BATCH * C * Hout * Wout;
    int idx = blockIdx.x * 256 + threadIdx.x;
    if (idx >= total) return;
    int c = idx % C; int r = idx / C;
    int x = r % Wout; r /= Wout;
    int y = r % Hout; int b = r / Hout;
    const int rs = Win * C;
    const ushort_t* p = in + (((size_t)b * Hin + 2 * y) * Win + 2 * x) * C + c;
    float m = b2f(p[0]);
    m = fmaxf(m, b2f(p[C])); m = fmaxf(m, b2f(p[2 * C]));
    m = fmaxf(m, b2f(p[rs])); m = fmaxf(m, b2f(p[rs + C])); m = fmaxf(m, b2f(p[rs + 2 * C]));
    m = fmaxf(m, b2f(p[2 * rs])); m = fmaxf(m, b2f(p[2 * rs + C])); m = fmaxf(m, b2f(p[2 * rs + 2 * C]));
    out[(((size_t)b * OHp + y + OPAD) * OWp + x + OPAD) * C + c] = f2bf(m);
}

// ---------- pool5: NHWC bf16 -> P fp32 [b][m][d] + PB bf16 [b*88+m][d] + XfPad ----------
__global__ void pool5_k(const ushort_t* __restrict__ in, float* __restrict__ P,
                        ushort_t* __restrict__ PB, ushort_t* __restrict__ XfPad) {
    int total = BATCH * 256 * MM;
    int idx = blockIdx.x * 256 + threadIdx.x;
    if (idx >= total) return;
    int c = idx % 256; int r = idx / 256;
    int x = r % W5P; r /= W5P;
    int y = r % H5P; int b = r / H5P;
    const int rs = W2P * 256;
    const ushort_t* p = in + (((size_t)b * H2P + 2 * y) * W2P + 2 * x) * 256 + c;
    float m = b2f(p[0]);
    m = fmaxf(m, b2f(p[256])); m = fmaxf(m, b2f(p[512]));
    m = fmaxf(m, b2f(p[rs])); m = fmaxf(m, b2f(p[rs + 256])); m = fmaxf(m, b2f(p[rs + 512]));
    m = fmaxf(m, b2f(p[2 * rs])); m = fmaxf(m, b2f(p[2 * rs + 256])); m = fmaxf(m, b2f(p[2 * rs + 512]));
    int mm = y * W5P + x;
    size_t o = ((size_t)b * MM + mm) * 256 + c;
    P[o] = m;
    ushort_t mb = f2bf(m);
    PB[o] = mb;
    if (b == 0) XfPad[(size_t)(mm + 1) * 256 + c] = mb;
}

// ---------- v[c] = max_m xc[c*88+m] ----------
__global__ void vmax_k(const float* __restrict__ xc, float* __restrict__ v) {
    int c = blockIdx.x * 64 + threadIdx.x;
    float m = -INFINITY;
    for (int j = 0; j < MM; ++j) m = fmaxf(m, xc[(size_t)c * MM + j]);
    v[c] = m;
}

__global__ void xhat_k(const float* __restrict__ v, const float* __restrict__ wt,
                       const float* __restrict__ bt, float* __restrict__ xhat) {
    __shared__ float lv[256];
    for (int j = threadIdx.x; j < 256; j += 256) lv[j] = v[j];
    __syncthreads();
    int idx = blockIdx.x * 256 + threadIdx.x;
    if (idx >= DD * MM) return;
    int k = idx % MM, o = idx / MM;
    float acc = bt[o];
    for (int i = 0; i < 256; ++i) acc = fmaf(lv[i], wt[(i * 256 + o) * MM + k], acc);
    xhat[idx] = acc;
}

__global__ void s1_k(const float* __restrict__ Y1, float* __restrict__ S1) {
    int idx = blockIdx.x * 256 + threadIdx.x;
    if (idx >= T_EX * 512) return;
    int c = idx % 512, t = idx / 512;
    float acc = 0.f;
    for (int m = 0; m < MM; ++m) acc += Y1[(m * T_EX + t) * 512 + c];
    S1[idx] = acc;
}

// h1 = lrelu(S_t - (t==0)*Y1 + bs1) -> bf16 [n][512]
__global__ void h1_k(const float* __restrict__ Y1, const float* __restrict__ S1,
                     const float* __restrict__ bs1, ushort_t* __restrict__ h1b) {
    int idx = blockIdx.x * 256 + threadIdx.x;
    if (idx >= TM * 512) return;
    int c = idx % 512; int n = idx / 512;
    int t = n % T_EX;
    float val = S1[t * 512 + c] + bs1[c];
    if (t == 0) val -= Y1[idx];
    h1b[idx] = f2bf(lrelu(val));
}

__global__ void s2_k(const float* __restrict__ Y2, float* __restrict__ S2) {
    int idx = blockIdx.x * 256 + threadIdx.x;
    if (idx >= T_EX * 256) return;
    int c = idx % 256, t = idx / 256;
    float acc = 0.f;
    for (int m = 0; m < MM; ++m) acc += Y2[(m * T_EX + t) * 256 + c];
    S2[idx] = acc;
}

__global__ void h2_k(const float* __restrict__ Y2, const float* __restrict__ S2,
                     const float* __restrict__ bs2, float* __restrict__ h2) {
    int idx = blockIdx.x * 256 + threadIdx.x;
    if (idx >= TM * 256) return;
    int c = idx % 256; int n = idx / 256;
    int t = n % T_EX;
    float val = S2[t * 256 + c] + bs2[c];
    if (t == 0) val -= Y2[idx];
    h2[idx] = lrelu(val);
}

__global__ void v1vx_k(const float* __restrict__ h2, const float* __restrict__ xhat,
                       float* __restrict__ V1, float* __restrict__ Vx) {
    int idx = blockIdx.x * 256 + threadIdx.x;
    if (idx >= DD * MM) return;
    int m = idx % MM, d = idx / MM;
    float mx = -INFINITY;
    for (int t = 0; t < T_EX; ++t) mx = fmaxf(mx, h2[(m * T_EX + t) * 256 + d]);
    V1[idx] = mx;
    Vx[idx] = mx + xhat[idx];
}

// G (y=0) and Hh (y=1) in one launch
__global__ void lin88_k(const float* __restrict__ Wg, const float* __restrict__ bg,
                        const float* __restrict__ Wh, const float* __restrict__ bh,
                        const float* __restrict__ Vin, float* __restrict__ Gout,
                        float* __restrict__ Hout) {
    int idx = blockIdx.x * 256 + threadIdx.x;
    if (idx >= DD * MM) return;
    const float* W = blockIdx.y ? Wh : Wg;
    const float* bias = blockIdx.y ? bh : bg;
    float* out = blockIdx.y ? Hout : Gout;
    int m = idx % MM, o = idx / MM;
    const float* wr = W + o * 256;
    float acc = bias[o];
    for (int i = 0; i < 256; ++i) acc = fmaf(wr[i], Vin[i * MM + m], acc);
    out[idx] = acc;
}

__global__ void smat_k(const float* __restrict__ Hh, const float* __restrict__ G,
                       float* __restrict__ Sm) {
    int idx = blockIdx.x * 256 + threadIdx.x;
    if (idx >= MM * MM) return;
    int i = idx % MM, j = idx / MM;
    float acc = 0.f;
    for (int c = 0; c < 256; ++c) acc = fmaf(Hh[c * MM + j], G[c * MM + i], acc);
    Sm[idx] = acc;
}

__global__ void softmax_k(const float* __restrict__ S, float* __restrict__ A2) {
    int j = blockIdx.x; int i = threadIdx.x;
    __shared__ float red[128];
    float val = (i < MM) ? S[j * MM + i] : -INFINITY;
    red[i] = val; __syncthreads();
    for (int s = 64; s > 0; s >>= 1) {
        if (i < s) red[i] = fmaxf(red[i], red[i + s]);
        __syncthreads();
    }
    float mx = red[0]; __syncthreads();
    float e = (i < MM) ? expf(val - mx) : 0.f;
    red[i] = e; __syncthreads();
    for (int s = 64; s > 0; s >>= 1) {
        if (i < s) red[i] += red[i + s];
        __syncthreads();
    }
    float inv = 1.f / red[0];
    if (i < MM) A2[j * MM + i] = e * inv;
}

__global__ void t1_k(const float* __restrict__ V1, const float* __restrict__ wc1,
                     float* __restrict__ t1) {
    int idx = blockIdx.x * 256 + threadIdx.x;
    if (idx >= MM * 384) return;
    int c = idx % 384, m = idx / 384;
    float acc = 0.f;
    for (int d = 0; d < 256; ++d) acc = fmaf(V1[d * MM + m], wc1[d * 384 + c], acc);
    t1[idx] = acc;
}

__global__ void c1_k(const float* __restrict__ A2, const float* __restrict__ t1,
                     const float* __restrict__ bc1, float* __restrict__ c1) {
    int idx = blockIdx.x * 256 + threadIdx.x;
    if (idx >= MM * 384) return;
    int c = idx % 384, j = idx / 384;
    float acc = bc1[c];
    for (int i = 0; i < MM; ++i) acc = fmaf(A2[j * MM + i], t1[i * 384 + c], acc);
    c1[idx] = lrelu(acc);
}

__global__ void t2_k(const float* __restrict__ c1, const float* __restrict__ wc2,
                     float* __restrict__ t2) {
    int idx = blockIdx.x * 256 + threadIdx.x;
    if (idx >= MM * 256) return;
    int c = idx % 256, m = idx / 256;
    const float* cr = c1 + m * 384;
    float acc = 0.f;
    for (int d = 0; d < 384; ++d) acc = fmaf(cr[d], wc2[d * 256 + c], acc);
    t2[idx] = acc;
}

__global__ void v2_k(const float* __restrict__ A2, const float* __restrict__ t2,
                     const float* __restrict__ bc2, float* __restrict__ V2m) {
    int idx = blockIdx.x * 256 + threadIdx.x;
    if (idx >= MM * 256) return;
    int c = idx % 256, j = idx / 256;
    float acc = bc2[c];
    for (int i = 0; i < MM; ++i) acc = fmaf(A2[j * MM + i], t2[i * 256 + c], acc);
    V2m[idx] = lrelu(acc);
}

__global__ void final_k(const float* __restrict__ Xf2, const float* __restrict__ V2m,
                        float* __restrict__ out) {
    __shared__ float red[256];
    float acc = 0.f;
    for (int idx = threadIdx.x; idx < DD * MM; idx += 256)
        acc = fmaf(Xf2[idx], V2m[idx], acc);
    red[threadIdx.x] = acc; __syncthreads();
    for (int s = 128; s > 0; s >>= 1) {
        if (threadIdx.x < s) red[threadIdx.x] += red[threadIdx.x + s];
        __syncthreads();
    }
    if (threadIdx.x == 0) out[0] = red[0];
}

extern "C" void kernel_launch(void* const* d_in, const int* in_sizes, int n_in,
                              void* d_out, int out_size, void* d_ws, size_t ws_size,
                              hipStream_t stream) {
    const float* search = (const float*)d_in[0];
    const float* exemp  = (const float*)d_in[1];
    const float* aw1 = (const float*)d_in[2];  const float* ab1 = (const float*)d_in[3];
    const float* aw2 = (const float*)d_in[4];  const float* ab2 = (const float*)d_in[5];
    const float* aw3 = (const float*)d_in[6];  const float* ab3 = (const float*)d_in[7];
    const float* aw4 = (const float*)d_in[8];  const float* ab4 = (const float*)d_in[9];
    const float* aw5 = (const float*)d_in[10]; const float* ab5 = (const float*)d_in[11];
    const float* wcd = (const float*)d_in[12]; const float* bcd = (const float*)d_in[13];
    const float* wt  = (const float*)d_in[14]; const float* bt  = (const float*)d_in[15];
    const float* ws1 = (const float*)d_in[16]; const float* bs1 = (const float*)d_in[17];
    const float* ws2 = (const float*)d_in[18]; const float* bs2 = (const float*)d_in[19];
    const float* wg  = (const float*)d_in[20]; const float* bg  = (const float*)d_in[21];
    const float* wh  = (const float*)d_in[22]; const float* bh  = (const float*)d_in[23];
    const float* wc1 = (const float*)d_in[24]; const float* bc1 = (const float*)d_in[25];
    const float* wc2 = (const float*)d_in[26]; const float* bc2 = (const float*)d_in[27];

    float* ws = (float*)d_ws;
    float* R1 = ws;
    float* R2 = ws + 3870720;
    float* R3 = ws + 7544832;
    float* Wg = ws + 8628864;

    ushort_t* in1p  = (ushort_t*)R1;
    ushort_t* c1out = (ushort_t*)R2;
    ushort_t* p1out = (ushort_t*)R3;
    ushort_t* c2out = (ushort_t*)R1;
    ushort_t* p2out = (ushort_t*)R2;
    ushort_t* c3out = (ushort_t*)(R2 + 775200);
    ushort_t* c4out = (ushort_t*)R1;
    ushort_t* c5out = (ushort_t*)R3;
    ushort_t* WT    = (ushort_t*)Wg;

    // ---- conv stack ----
    zfill_k<<<(965500 + 255) / 256, 256, 0, stream>>>((float4*)R1, 965500);
    prep1_k<<<(BATCH * H0 * W0 + 255) / 256, 256, 0, stream>>>(search, exemp, in1p);
    wprep_k<<<(4352 + 255) / 256, 256, 0, stream>>>(aw1, WT, 11, 12, 11, 4, 3, 17, 4352);
    conv_mfma2<4, false><<<dim3(106, 1, BATCH), 256, 0, stream>>>(
        in1p, WT, ab1, c1out, HP1, WP1, 4, W1, H1 * W1, 17, 12, H1, W1, 0, 64);
    zfill_k<<<(270504 + 255) / 256, 256, 0, stream>>>((float4*)R3, 270504);
    pool_nhwc<<<(BATCH * 64 * H1P * W1P + 255) / 256, 256, 0, stream>>>(
        c1out, p1out, 64, H1, W1, H1P, W1P, 51, 39, 2);
    wprep_k<<<(38400 + 255) / 256, 256, 0, stream>>>(aw2, WT, 5, 5, 5, 64, 64, 50, 38400);
    conv_mfma2<1, true><<<dim3(26, 3, BATCH), 256, 0, stream>>>(
        p1out, WT, ab2, c2out, 51, 39, 64, W1P, H1P * W1P, 50, 5, H1P, W1P, 0, 192);
    zfill_k<<<(581400 + 255) / 256, 256, 0, stream>>>((float4*)R2, 581400);
    pool_nhwc<<<(BATCH * 192 * H2P * W2P + 255) / 256, 256, 0, stream>>>(
        c2out, p2out, 192, H1P, W1P, H2P, W2P, 25, 19, 1);
    wprep_k<<<(82944 + 255) / 256, 256, 0, stream>>>(aw3, WT, 3, 3, 3, 192, 192, 54, 82944);
    conv_mfma2<1, true><<<dim3(7, 6, BATCH), 256, 0, stream>>>(
        p2out, WT, ab3, c3out, 25, 19, 192, W2P, H2P * W2P, 54, 3, 25, 19, 1, 384);
    zfill_k<<<(258400 + 255) / 256, 256, 0, stream>>>((float4*)R1, 258400);
    wprep_k<<<(110592 + 255) / 256, 256, 0, stream>>>(aw4, WT, 3, 3, 3, 384, 384, 108, 110592);
    conv_mfma2<1, true><<<dim3(7, 4, BATCH), 256, 0, stream>>>(
        c3out, WT, ab4, c4out, 25, 19, 384, W2P, H2P * W2P, 108, 3, 25, 19, 1, 256);
    wprep_k<<<(73728 + 255) / 256, 256, 0, stream>>>(aw5, WT, 3, 3, 3, 256, 256, 72, 73728);
    conv_mfma2<1, true><<<dim3(7, 4, BATCH), 256, 0, stream>>>(
        c4out, WT, ab5, c5out, 25, 19, 256, W2P, H2P * W2P, 72, 3, H2P, W2P, 0, 256);

    // ---- layout: tail region in R1 ----
    float*    P      = R1 + 2417664;                 // [17][88][256] fp32
    ushort_t* PB     = (ushort_t*)(R1 + 2800640);    // [17*88][256] bf16
    ushort_t* XfPad  = (ushort_t*)(R1 + 2992128);    // [90][256] bf16
    float*    xc     = R1 + 3003648;                 // [256][88]

    // ---- GCN/tail weight tiles (Wg free after conv5 enqueued; stream-ordered) ----
    ushort_t* WS1T = (ushort_t*)Wg;                  // 8 ocb x 8 ks  = 131072 bf16
    ushort_t* WS2T = (ushort_t*)(Wg + 65536);        // 4 x 16        = 131072
    ushort_t* WCDT = (ushort_t*)(Wg + 131072);       // 4 x 24        = 196608
    wprep2_k<0><<<(16384 + 255) / 256, 256, 0, stream>>>(ws1, WS1T, 1, 512, 8, 16384);
    wprep2_k<0><<<(16384 + 255) / 256, 256, 0, stream>>>(ws2, WS2T, 1, 256, 16, 16384);
    wprep2_k<1><<<(24576 + 255) / 256, 256, 0, stream>>>(wcd, WCDT, 0, 0, 24, 24576);

    // ---- pool5: P fp32 + PB bf16 + XfPad interior ----
    zfill_k<<<(2880 + 255) / 256, 256, 0, stream>>>((float4*)XfPad, 2880);   // rows 0 & 89
    pool5_k<<<(BATCH * 256 * MM + 255) / 256, 256, 0, stream>>>(c5out, P, PB, XfPad);
    float* Xf2 = P;

    // ---- tail buffers ----
    float* v_   = R1 + 0;
    float* xhat = R1 + 1024;
    float* Y1   = R1 + 23552;      // [1408][512]
    float* S1   = R1 + 744448;
    ushort_t* h1b = (ushort_t*)(R1 + 752640);   // [1408][512] bf16
    float* Y2   = R1 + 1473536;    // [1408][256]
    float* S2   = R1 + 1833984;
    float* h2   = R1 + 1838080;
    float* V1   = R1 + 2198528;
    float* Vx   = R1 + 2221056;
    float* G    = R1 + 2243584;
    float* Hh   = R1 + 2266112;
    float* Sm   = R1 + 2288640;
    float* A2   = R1 + 2296832;
    float* t1   = R1 + 2305024;
    float* c1   = R1 + 2338816;
    float* t2   = R1 + 2372608;
    float* V2m  = R1 + 2395136;

    // conv_deconv branch: xc = Wcd @ XfPad-cols (MFMA), then rowmax, then xhat
    gemm_mfma<0, true, false><<<dim3(2, 4), 256, 0, stream>>>(
        XfPad, WCDT, bcd, xc, 256, MM, 24, 1, MM);
    vmax_k<<<4, 64, 0, stream>>>(xc, v_);
    xhat_k<<<(DD * MM + 255) / 256, 256, 0, stream>>>(v_, wt, bt, xhat);

    // st GCN: Y1 = nodes @ ws1 (MFMA), structured A1, Y2 = h1 @ ws2 (MFMA)
    gemm_mfma<1, false, true><<<dim3(22, 8), 256, 0, stream>>>(
        PB, WS1T, nullptr, Y1, 256, TM, 8, 512, 1);
    s1_k<<<(T_EX * 512 + 255) / 256, 256, 0, stream>>>(Y1, S1);
    h1_k<<<(TM * 512 + 255) / 256, 256, 0, stream>>>(Y1, S1, bs1, h1b);
    gemm_mfma<0, false, true><<<dim3(22, 4), 256, 0, stream>>>(
        h1b, WS2T, nullptr, Y2, 512, TM, 16, 256, 1);
    s2_k<<<(T_EX * 256 + 255) / 256, 256, 0, stream>>>(Y2, S2);
    h2_k<<<(TM * 256 + 255) / 256, 256, 0, stream>>>(Y2, S2, bs2, h2);
    v1vx_k<<<(DD * MM + 255) / 256, 256, 0, stream>>>(h2, xhat, V1, Vx);

    // dynamic graph
    lin88_k<<<dim3((DD * MM + 255) / 256, 2), 256, 0, stream>>>(wg, bg, wh, bh, Vx, G, Hh);
    smat_k<<<(MM * MM + 255) / 256, 256, 0, stream>>>(Hh, G, Sm);
    softmax_k<<<MM, 128, 0, stream>>>(Sm, A2);

    // ct GCN
    t1_k<<<(MM * 384 + 255) / 256, 256, 0, stream>>>(V1, wc1, t1);
    c1_k<<<(MM * 384 + 255) / 256, 256, 0, stream>>>(A2, t1, bc1, c1);
    t2_k<<<(MM * 256 + 255) / 256, 256, 0, stream>>>(c1, wc2, t2);
    v2_k<<<(MM * 256 + 255) / 256, 256, 0, stream>>>(A2, t2, bc2, V2m);

    final_k<<<1, 256, 0, stream>>>(Xf2, V2m, (float*)d_out);
}

// Round 6
// 597.320 us; speedup vs baseline: 16.2619x; 1.0347x over previous
//
#include <hip/hip_runtime.h>
#include <hip/hip_bf16.h>
#include <math.h>

// ---------- dims ----------
#define BATCH 17
#define T_EX 16
#define H0 383
#define W0 287
#define C1 64
#define H1 95
#define W1 71
#define H1P 47
#define W1P 35
#define C2 192
#define H2P 23
#define W2P 17
#define C3 384
#define C45 256
#define H5P 11
#define W5P 8
#define DD 256
#define MM 88
#define TM 1408

#define HP1 389
#define WP1 292

typedef unsigned short ushort_t;
typedef __attribute__((ext_vector_type(8))) short short8;
typedef __attribute__((ext_vector_type(4))) float f32x4;

__device__ __forceinline__ float lrelu(float v) { return v > 0.f ? v : 0.01f * v; }

__device__ __forceinline__ ushort_t f2bf(float f) {
    unsigned int u = __float_as_uint(f);
    unsigned int r = (u + 0x7fffu + ((u >> 16) & 1u)) >> 16;
    return (ushort_t)r;
}
__device__ __forceinline__ float b2f(ushort_t b) {
    return __uint_as_float(((unsigned int)b) << 16);
}

// ---------- zero fill ----------
__global__ void zfill_k(float4* __restrict__ p, int n4) {
    int idx = blockIdx.x * 256 + threadIdx.x;
    if (idx < n4) p[idx] = (float4){0.f, 0.f, 0.f, 0.f};
}

// ---------- conv1 input prep: fp32 NCHW -> bf16 NHWC padded (C=4, pad 2) ----------
__global__ void prep1_k(const float* __restrict__ search, const float* __restrict__ exemp,
                        ushort_t* __restrict__ out) {
    int idx = blockIdx.x * 256 + threadIdx.x;
    if (idx >= BATCH * H0 * W0) return;
    int ix = idx % W0; int t = idx / W0;
    int iy = t % H0; int b = t / H0;
    const float* src = (b == 0) ? search : exemp + (size_t)(b - 1) * 3 * H0 * W0;
    const int hw = H0 * W0;
    float v0 = src[iy * W0 + ix];
    float v1 = src[hw + iy * W0 + ix];
    float v2 = src[2 * hw + iy * W0 + ix];
    ushort4 o;
    o.x = f2bf(v0); o.y = f2bf(v1); o.z = f2bf(v2); o.w = 0;
    *(ushort4*)&out[(((size_t)b * HP1 + iy + 2) * WP1 + ix + 2) * 4] = o;
}

// ---------- conv weight prep: OIHW fp32 -> bf16 MFMA tiles, K-order (ky,kx,ic) ----------
__global__ void wprep_k(const float* __restrict__ w, ushort_t* __restrict__ out,
                        int KH, int KWl, int KWr, int CINl, int CINr,
                        int NKS, int nch) {
    int idx = blockIdx.x * 256 + threadIdx.x;
    if (idx >= nch) return;
    int c = idx & 255;
    int rest = idx >> 8;
    int ks = rest % NKS;
    int ocb = rest / NKS;
    int k8 = c >> 6, m = c & 63;
    int oc = ocb * 64 + m;
    int KWC = KWl * CINl;
    ushort_t* o = out + (size_t)idx * 8;
#pragma unroll
    for (int j = 0; j < 8; ++j) {
        int kg = ks * 32 + k8 * 8 + j;
        int ky = kg / KWC; int rem = kg - ky * KWC;
        int kx = rem / CINl; int ic = rem - kx * CINl;
        float v = 0.f;
        if (ky < KH && kx < KWr && ic < CINr)
            v = w[(((size_t)oc * CINr + ic) * KH + ky) * KWr + kx];
        o[j] = f2bf(v);
    }
}

// ---------- generic GEMM weight prep ----------
template <int MODE>
__global__ void wprep2_k(const float* __restrict__ src, ushort_t* __restrict__ out,
                         int sa, int sk, int NKS, int nch) {
    int idx = blockIdx.x * 256 + threadIdx.x;
    if (idx >= nch) return;
    int c = idx & 255;
    int rest = idx >> 8;
    int ks = rest % NKS;
    int ocb = rest / NKS;
    int k8 = c >> 6, m = c & 63;
    int oc = ocb * 64 + m;
    ushort_t* o = out + (size_t)idx * 8;
#pragma unroll
    for (int j = 0; j < 8; ++j) {
        int kg = ks * 32 + k8 * 8 + j;
        float v;
        if (MODE == 0) v = src[(size_t)oc * sa + (size_t)kg * sk];
        else           v = src[(size_t)oc * 768 + (kg & 255) * 3 + (kg >> 8)];
        o[j] = f2bf(v);
    }
}

// ====================================================================
// bf16 MFMA implicit-GEMM conv, NHWC padded input, table-driven gather,
// 2-stage software pipeline, double-buffered LDS, ONE barrier/step.
// ====================================================================
template <int STRIDE, bool A16>
__global__ __launch_bounds__(256) void conv_mfma2(
    const ushort_t* __restrict__ inp, const ushort_t* __restrict__ wt,
    const float* __restrict__ bias, ushort_t* __restrict__ out,
    int Hp, int Wp, int C, int Wout, int HW, int NKS, int KWl,
    int OHp, int OWp, int OPAD, int COUT) {
    const int tid = threadIdx.x;
    const int wv = tid >> 6, lane = tid & 63;
    const int n_blk = blockIdx.x * 64;
    const int ocb = blockIdx.y;
    const int b = blockIdx.z;

    __shared__ ushort_t As[2][2048];
    __shared__ ushort_t Bs[2][2048];
    __shared__ int offs[448];

    const int KWC = KWl * C;
    for (int g = tid; g < NKS * 4; g += 256) {
        int kg = g * 8;
        int ky = kg / KWC; int rem = kg - ky * KWC;
        int kx = rem / C; int c8 = rem - kx * C;
        offs[g] = (ky * Wp + kx) * C + c8;
    }

    const ushort_t* inb = inp + (size_t)b * Hp * Wp * C;
    int n_g = n_blk + lane;
    int n_gc = n_g < HW ? n_g : HW - 1;
    int oy = n_gc / Wout, ox = n_gc - oy * Wout;
    const int base0 = (oy * STRIDE * Wp + ox * STRIDE) * C;

    f32x4 acc[4];
#pragma unroll
    for (int cn = 0; cn < 4; ++cn) acc[cn] = (f32x4){0.f, 0.f, 0.f, 0.f};

    const ushort_t* wblk = wt + (size_t)ocb * NKS * 2048;
    const int quad = lane >> 4, l16 = lane & 15;

    __syncthreads();   // offs table ready

    // ---- prologue: stage step 0 ----
    {
        const short8 aval = *(const short8*)(wblk + tid * 8);
        const ushort_t* src = inb + base0 + offs[wv];
        short8 bval;
        if (A16) bval = *(const short8*)src;
        else {
            union { uint2 u[2]; short8 s; } uu;
            uu.u[0] = *(const uint2*)src;
            uu.u[1] = *(const uint2*)(src + 4);
            bval = uu.s;
        }
        *(short8*)&As[0][tid * 8] = aval;
        *(short8*)&Bs[0][tid * 8] = bval;
    }
    __syncthreads();

    for (int ks = 0; ks < NKS; ++ks) {
        const int cur = ks & 1, nxt = cur ^ 1;
        short8 a2, b2;
        const bool more = (ks + 1 < NKS);
        if (more) {
            a2 = *(const short8*)(wblk + (ks + 1) * 2048 + tid * 8);
            const ushort_t* src = inb + base0 + offs[(ks + 1) * 4 + wv];
            if (A16) b2 = *(const short8*)src;
            else {
                union { uint2 u[2]; short8 s; } uu;
                uu.u[0] = *(const uint2*)src;
                uu.u[1] = *(const uint2*)(src + 4);
                b2 = uu.s;
            }
        }
        // compute from cur buffer
        {
            const short8 af = *(const short8*)&As[cur][(quad * 64 + wv * 16 + l16) * 8];
#pragma unroll
            for (int cn = 0; cn < 4; ++cn) {
                const short8 bfr = *(const short8*)&Bs[cur][(quad * 64 + cn * 16 + l16) * 8];
                acc[cn] = __builtin_amdgcn_mfma_f32_16x16x32_bf16(af, bfr, acc[cn], 0, 0, 0);
            }
        }
        if (more) {
            *(short8*)&As[nxt][tid * 8] = a2;
            *(short8*)&Bs[nxt][tid * 8] = b2;
        }
        __syncthreads();
    }

    const int oc0 = ocb * 64 + wv * 16 + quad * 4;
    const float b0 = bias[oc0], b1 = bias[oc0 + 1], b2 = bias[oc0 + 2], b3 = bias[oc0 + 3];
#pragma unroll
    for (int cn = 0; cn < 4; ++cn) {
        int n = n_blk + cn * 16 + l16;
        if (n < HW) {
            int y = n / Wout, x = n - y * Wout;
            size_t base = (((size_t)b * OHp + y + OPAD) * OWp + x + OPAD) * COUT + oc0;
            ushort4 o;
            o.x = f2bf(fmaxf(acc[cn][0] + b0, 0.f));
            o.y = f2bf(fmaxf(acc[cn][1] + b1, 0.f));
            o.z = f2bf(fmaxf(acc[cn][2] + b2, 0.f));
            o.w = f2bf(fmaxf(acc[cn][3] + b3, 0.f));
            *(ushort4*)&out[base] = o;
        }
    }
}

// ====================================================================
// Generic bf16 MFMA GEMM (pipelined, double-buffered, one barrier/step).
// out[oc][n] = sum_k A[oc][k]*B[k][n]; B[k][n] = Bsrc[row(n)*RS + k].
// MODE 0: row = n. MODE 1: row = (1+(n&15))*88 + (n>>4).
// ====================================================================
template <int MODE, bool HASBIAS, bool SC1>
__global__ __launch_bounds__(256) void gemm_mfma(
    const ushort_t* __restrict__ Bsrc, const ushort_t* __restrict__ wt,
    const float* __restrict__ bias, float* __restrict__ out,
    int RS, int N, int NKS, int sn, int sc) {
    const int tid = threadIdx.x;
    const int wv = tid >> 6, lane = tid & 63;
    const int n_blk = blockIdx.x * 64;
    const int ocb = blockIdx.y;

    __shared__ ushort_t As[2][2048];
    __shared__ ushort_t Bs[2][2048];

    int n_g = n_blk + lane;
    int n_gc = n_g < N ? n_g : N - 1;
    int row = (MODE == 1) ? (1 + (n_gc & 15)) * MM + (n_gc >> 4) : n_gc;
    const size_t base0 = (size_t)row * RS;

    f32x4 acc[4];
#pragma unroll
    for (int cn = 0; cn < 4; ++cn) acc[cn] = (f32x4){0.f, 0.f, 0.f, 0.f};

    const ushort_t* wblk = wt + (size_t)ocb * NKS * 2048;
    const int quad = lane >> 4, l16 = lane & 15;

    {
        const short8 aval = *(const short8*)(wblk + tid * 8);
        const short8 bval = *(const short8*)(Bsrc + base0 + wv * 8);
        *(short8*)&As[0][tid * 8] = aval;
        *(short8*)&Bs[0][tid * 8] = bval;
    }
    __syncthreads();

    for (int ks = 0; ks < NKS; ++ks) {
        const int cur = ks & 1, nxt = cur ^ 1;
        short8 a2, b2;
        const bool more = (ks + 1 < NKS);
        if (more) {
            a2 = *(const short8*)(wblk + (ks + 1) * 2048 + tid * 8);
            b2 = *(const short8*)(Bsrc + base0 + (ks + 1) * 32 + wv * 8);
        }
        {
            const short8 af = *(const short8*)&As[cur][(quad * 64 + wv * 16 + l16) * 8];
#pragma unroll
            for (int cn = 0; cn < 4; ++cn) {
                const short8 bfr = *(const short8*)&Bs[cur][(quad * 64 + cn * 16 + l16) * 8];
                acc[cn] = __builtin_amdgcn_mfma_f32_16x16x32_bf16(af, bfr, acc[cn], 0, 0, 0);
            }
        }
        if (more) {
            *(short8*)&As[nxt][tid * 8] = a2;
            *(short8*)&Bs[nxt][tid * 8] = b2;
        }
        __syncthreads();
    }

    const int oc0 = ocb * 64 + wv * 16 + quad * 4;
    float bb[4] = {0.f, 0.f, 0.f, 0.f};
    if (HASBIAS) { bb[0] = bias[oc0]; bb[1] = bias[oc0+1]; bb[2] = bias[oc0+2]; bb[3] = bias[oc0+3]; }
#pragma unroll
    for (int cn = 0; cn < 4; ++cn) {
        int n = n_blk + cn * 16 + l16;
        if (n < N) {
            if (SC1) {
                float4 o;
                o.x = acc[cn][0] + bb[0]; o.y = acc[cn][1] + bb[1];
                o.z = acc[cn][2] + bb[2]; o.w = acc[cn][3] + bb[3];
                *(float4*)&out[(size_t)n * sn + oc0] = o;
            } else {
#pragma unroll
                for (int reg = 0; reg < 4; ++reg)
                    out[(size_t)n * sn + (size_t)(oc0 + reg) * sc] = acc[cn][reg] + bb[reg];
            }
        }
    }
}

// ---------- maxpool k3 s2 VALID, NHWC bf16 ----------
__global__ void pool_nhwc(const ushort_t* __restrict__ in, ushort_t* __restrict__ out,
                          int C, int Hin, int Win, int Hout, int Wout,
                          int OHp, int OWp, int OPAD) {
    int total = BATCH * C * Hout * Wout;
    int idx = blockIdx.x * 256 + threadIdx.x;
    if (idx >= total) return;
    int c = idx % C; int r = idx / C;
    int x = r % Wout; r /= Wout;
    int y = r % Hout; int b = r / Hout;
    const int rs = Win * C;
    const ushort_t* p = in + (((size_t)b * Hin + 2 * y) * Win + 2 * x) * C + c;
    float m = b2f(p[0]);
    m = fmaxf(m, b2f(p[C])); m = fmaxf(m, b2f(p[2 * C]));
    m = fmaxf(m, b2f(p[rs])); m = fmaxf(m, b2f(p[rs + C])); m = fmaxf(m, b2f(p[rs + 2 * C]));
    m = fmaxf(m, b2f(p[2 * rs])); m = fmaxf(m, b2f(p[2 * rs + C])); m = fmaxf(m, b2f(p[2 * rs + 2 * C]));
    out[(((size_t)b * OHp + y + OPAD) * OWp + x + OPAD) * C + c] = f2bf(m);
}

// ---------- pool5: NHWC bf16 -> P fp32 [b][m][d] + PB bf16 + XfPad ----------
__global__ void pool5_k(const ushort_t* __restrict__ in, float* __restrict__ P,
                        ushort_t* __restrict__ PB, ushort_t* __restrict__ XfPad) {
    int total = BATCH * 256 * MM;
    int idx = blockIdx.x * 256 + threadIdx.x;
    if (idx >= total) return;
    int c = idx % 256; int r = idx / 256;
    int x = r % W5P; r /= W5P;
    int y = r % H5P; int b = r / H5P;
    const int rs = W2P * 256;
    const ushort_t* p = in + (((size_t)b * H2P + 2 * y) * W2P + 2 * x) * 256 + c;
    float m = b2f(p[0]);
    m = fmaxf(m, b2f(p[256])); m = fmaxf(m, b2f(p[512]));
    m = fmaxf(m, b2f(p[rs])); m = fmaxf(m, b2f(p[rs + 256])); m = fmaxf(m, b2f(p[rs + 512]));
    m = fmaxf(m, b2f(p[2 * rs])); m = fmaxf(m, b2f(p[2 * rs + 256])); m = fmaxf(m, b2f(p[2 * rs + 512]));
    int mm = y * W5P + x;
    size_t o = ((size_t)b * MM + mm) * 256 + c;
    P[o] = m;
    ushort_t mb = f2bf(m);
    PB[o] = mb;
    if (b == 0) XfPad[(size_t)(mm + 1) * 256 + c] = mb;
}

// ---------- v[c] = max_m xc[c*88+m] ----------
__global__ void vmax_k(const float* __restrict__ xc, float* __restrict__ v) {
    int c = blockIdx.x * 64 + threadIdx.x;
    float m = -INFINITY;
    for (int j = 0; j < MM; ++j) m = fmaxf(m, xc[(size_t)c * MM + j]);
    v[c] = m;
}

__global__ void xhat_k(const float* __restrict__ v, const float* __restrict__ wt,
                       const float* __restrict__ bt, float* __restrict__ xhat) {
    __shared__ float lv[256];
    for (int j = threadIdx.x; j < 256; j += 256) lv[j] = v[j];
    __syncthreads();
    int idx = blockIdx.x * 256 + threadIdx.x;
    if (idx >= DD * MM) return;
    int k = idx % MM, o = idx / MM;
    float acc = bt[o];
    for (int i = 0; i < 256; ++i) acc = fmaf(lv[i], wt[(i * 256 + o) * MM + k], acc);
    xhat[idx] = acc;
}

__global__ void s1_k(const float* __restrict__ Y1, float* __restrict__ S1) {
    int idx = blockIdx.x * 256 + threadIdx.x;
    if (idx >= T_EX * 512) return;
    int c = idx % 512, t = idx / 512;
    float acc = 0.f;
    for (int m = 0; m < MM; ++m) acc += Y1[(m * T_EX + t) * 512 + c];
    S1[idx] = acc;
}

__global__ void h1_k(const float* __restrict__ Y1, const float* __restrict__ S1,
                     const float* __restrict__ bs1, ushort_t* __restrict__ h1b) {
    int idx = blockIdx.x * 256 + threadIdx.x;
    if (idx >= TM * 512) return;
    int c = idx % 512; int n = idx / 512;
    int t = n % T_EX;
    float val = S1[t * 512 + c] + bs1[c];
    if (t == 0) val -= Y1[idx];
    h1b[idx] = f2bf(lrelu(val));
}

__global__ void s2_k(const float* __restrict__ Y2, float* __restrict__ S2) {
    int idx = blockIdx.x * 256 + threadIdx.x;
    if (idx >= T_EX * 256) return;
    int c = idx % 256, t = idx / 256;
    float acc = 0.f;
    for (int m = 0; m < MM; ++m) acc += Y2[(m * T_EX + t) * 256 + c];
    S2[idx] = acc;
}

__global__ void h2_k(const float* __restrict__ Y2, const float* __restrict__ S2,
                     const float* __restrict__ bs2, float* __restrict__ h2) {
    int idx = blockIdx.x * 256 + threadIdx.x;
    if (idx >= TM * 256) return;
    int c = idx % 256; int n = idx / 256;
    int t = n % T_EX;
    float val = S2[t * 256 + c] + bs2[c];
    if (t == 0) val -= Y2[idx];
    h2[idx] = lrelu(val);
}

__global__ void v1vx_k(const float* __restrict__ h2, const float* __restrict__ xhat,
                       float* __restrict__ V1, float* __restrict__ Vx) {
    int idx = blockIdx.x * 256 + threadIdx.x;
    if (idx >= DD * MM) return;
    int m = idx % MM, d = idx / MM;
    float mx = -INFINITY;
    for (int t = 0; t < T_EX; ++t) mx = fmaxf(mx, h2[(m * T_EX + t) * 256 + d]);
    V1[idx] = mx;
    Vx[idx] = mx + xhat[idx];
}

__global__ void lin88_k(const float* __restrict__ Wg, const float* __restrict__ bg,
                        const float* __restrict__ Wh, const float* __restrict__ bh,
                        const float* __restrict__ Vin, float* __restrict__ Gout,
                        float* __restrict__ Hout) {
    int idx = blockIdx.x * 256 + threadIdx.x;
    if (idx >= DD * MM) return;
    const float* W = blockIdx.y ? Wh : Wg;
    const float* bias = blockIdx.y ? bh : bg;
    float* out = blockIdx.y ? Hout : Gout;
    int m = idx % MM, o = idx / MM;
    const float* wr = W + o * 256;
    float acc = bias[o];
    for (int i = 0; i < 256; ++i) acc = fmaf(wr[i], Vin[i * MM + m], acc);
    out[idx] = acc;
}

__global__ void smat_k(const float* __restrict__ Hh, const float* __restrict__ G,
                       float* __restrict__ Sm) {
    int idx = blockIdx.x * 256 + threadIdx.x;
    if (idx >= MM * MM) return;
    int i = idx % MM, j = idx / MM;
    float acc = 0.f;
    for (int c = 0; c < 256; ++c) acc = fmaf(Hh[c * MM + j], G[c * MM + i], acc);
    Sm[idx] = acc;
}

__global__ void softmax_k(const float* __restrict__ S, float* __restrict__ A2) {
    int j = blockIdx.x; int i = threadIdx.x;
    __shared__ float red[128];
    float val = (i < MM) ? S[j * MM + i] : -INFINITY;
    red[i] = val; __syncthreads();
    for (int s = 64; s > 0; s >>= 1) {
        if (i < s) red[i] = fmaxf(red[i], red[i + s]);
        __syncthreads();
    }
    float mx = red[0]; __syncthreads();
    float e = (i < MM) ? expf(val - mx) : 0.f;
    red[i] = e; __syncthreads();
    for (int s = 64; s > 0; s >>= 1) {
        if (i < s) red[i] += red[i + s];
        __syncthreads();
    }
    float inv = 1.f / red[0];
    if (i < MM) A2[j * MM + i] = e * inv;
}

__global__ void t1_k(const float* __restrict__ V1, const float* __restrict__ wc1,
                     float* __restrict__ t1) {
    int idx = blockIdx.x * 256 + threadIdx.x;
    if (idx >= MM * 384) return;
    int c = idx % 384, m = idx / 384;
    float acc = 0.f;
    for (int d = 0; d < 256; ++d) acc = fmaf(V1[d * MM + m], wc1[d * 384 + c], acc);
    t1[idx] = acc;
}

__global__ void c1_k(const float* __restrict__ A2, const float* __restrict__ t1,
                     const float* __restrict__ bc1, float* __restrict__ c1) {
    int idx = blockIdx.x * 256 + threadIdx.x;
    if (idx >= MM * 384) return;
    int c = idx % 384, j = idx / 384;
    float acc = bc1[c];
    for (int i = 0; i < MM; ++i) acc = fmaf(A2[j * MM + i], t1[i * 384 + c], acc);
    c1[idx] = lrelu(acc);
}

__global__ void t2_k(const float* __restrict__ c1, const float* __restrict__ wc2,
                     float* __restrict__ t2) {
    int idx = blockIdx.x * 256 + threadIdx.x;
    if (idx >= MM * 256) return;
    int c = idx % 256, m = idx / 256;
    const float* cr = c1 + m * 384;
    float acc = 0.f;
    for (int d = 0; d < 384; ++d) acc = fmaf(cr[d], wc2[d * 256 + c], acc);
    t2[idx] = acc;
}

__global__ void v2_k(const float* __restrict__ A2, const float* __restrict__ t2,
                     const float* __restrict__ bc2, float* __restrict__ V2m) {
    int idx = blockIdx.x * 256 + threadIdx.x;
    if (idx >= MM * 256) return;
    int c = idx % 256, j = idx / 256;
    float acc = bc2[c];
    for (int i = 0; i < MM; ++i) acc = fmaf(A2[j * MM + i], t2[i * 256 + c], acc);
    V2m[idx] = lrelu(acc);
}

__global__ void final_k(const float* __restrict__ Xf2, const float* __restrict__ V2m,
                        float* __restrict__ out) {
    __shared__ float red[256];
    float acc = 0.f;
    for (int idx = threadIdx.x; idx < DD * MM; idx += 256)
        acc = fmaf(Xf2[idx], V2m[idx], acc);
    red[threadIdx.x] = acc; __syncthreads();
    for (int s = 128; s > 0; s >>= 1) {
        if (threadIdx.x < s) red[threadIdx.x] += red[threadIdx.x + s];
        __syncthreads();
    }
    if (threadIdx.x == 0) out[0] = red[0];
}

extern "C" void kernel_launch(void* const* d_in, const int* in_sizes, int n_in,
                              void* d_out, int out_size, void* d_ws, size_t ws_size,
                              hipStream_t stream) {
    const float* search = (const float*)d_in[0];
    const float* exemp  = (const float*)d_in[1];
    const float* aw1 = (const float*)d_in[2];  const float* ab1 = (const float*)d_in[3];
    const float* aw2 = (const float*)d_in[4];  const float* ab2 = (const float*)d_in[5];
    const float* aw3 = (const float*)d_in[6];  const float* ab3 = (const float*)d_in[7];
    const float* aw4 = (const float*)d_in[8];  const float* ab4 = (const float*)d_in[9];
    const float* aw5 = (const float*)d_in[10]; const float* ab5 = (const float*)d_in[11];
    const float* wcd = (const float*)d_in[12]; const float* bcd = (const float*)d_in[13];
    const float* wt  = (const float*)d_in[14]; const float* bt  = (const float*)d_in[15];
    const float* ws1 = (const float*)d_in[16]; const float* bs1 = (const float*)d_in[17];
    const float* ws2 = (const float*)d_in[18]; const float* bs2 = (const float*)d_in[19];
    const float* wg  = (const float*)d_in[20]; const float* bg  = (const float*)d_in[21];
    const float* wh  = (const float*)d_in[22]; const float* bh  = (const float*)d_in[23];
    const float* wc1 = (const float*)d_in[24]; const float* bc1 = (const float*)d_in[25];
    const float* wc2 = (const float*)d_in[26]; const float* bc2 = (const float*)d_in[27];

    float* ws = (float*)d_ws;
    float* R1 = ws;
    float* R2 = ws + 3870720;
    float* R3 = ws + 7544832;
    float* Wg = ws + 8628864;

    ushort_t* in1p  = (ushort_t*)R1;
    ushort_t* c1out = (ushort_t*)R2;
    ushort_t* p1out = (ushort_t*)R3;
    ushort_t* c2out = (ushort_t*)R1;
    ushort_t* p2out = (ushort_t*)R2;
    ushort_t* c3out = (ushort_t*)(R2 + 775200);
    ushort_t* c4out = (ushort_t*)R1;
    ushort_t* c5out = (ushort_t*)R3;
    ushort_t* WT    = (ushort_t*)Wg;

    // ---- conv stack ----
    zfill_k<<<(965500 + 255) / 256, 256, 0, stream>>>((float4*)R1, 965500);
    prep1_k<<<(BATCH * H0 * W0 + 255) / 256, 256, 0, stream>>>(search, exemp, in1p);
    wprep_k<<<(4352 + 255) / 256, 256, 0, stream>>>(aw1, WT, 11, 12, 11, 4, 3, 17, 4352);
    conv_mfma2<4, false><<<dim3(106, 1, BATCH), 256, 0, stream>>>(
        in1p, WT, ab1, c1out, HP1, WP1, 4, W1, H1 * W1, 17, 12, H1, W1, 0, 64);
    zfill_k<<<(270504 + 255) / 256, 256, 0, stream>>>((float4*)R3, 270504);
    pool_nhwc<<<(BATCH * 64 * H1P * W1P + 255) / 256, 256, 0, stream>>>(
        c1out, p1out, 64, H1, W1, H1P, W1P, 51, 39, 2);
    wprep_k<<<(38400 + 255) / 256, 256, 0, stream>>>(aw2, WT, 5, 5, 5, 64, 64, 50, 38400);
    conv_mfma2<1, true><<<dim3(26, 3, BATCH), 256, 0, stream>>>(
        p1out, WT, ab2, c2out, 51, 39, 64, W1P, H1P * W1P, 50, 5, H1P, W1P, 0, 192);
    zfill_k<<<(581400 + 255) / 256, 256, 0, stream>>>((float4*)R2, 581400);
    pool_nhwc<<<(BATCH * 192 * H2P * W2P + 255) / 256, 256, 0, stream>>>(
        c2out, p2out, 192, H1P, W1P, H2P, W2P, 25, 19, 1);
    wprep_k<<<(82944 + 255) / 256, 256, 0, stream>>>(aw3, WT, 3, 3, 3, 192, 192, 54, 82944);
    conv_mfma2<1, true><<<dim3(7, 6, BATCH), 256, 0, stream>>>(
        p2out, WT, ab3, c3out, 25, 19, 192, W2P, H2P * W2P, 54, 3, 25, 19, 1, 384);
    zfill_k<<<(258400 + 255) / 256, 256, 0, stream>>>((float4*)R1, 258400);
    wprep_k<<<(110592 + 255) / 256, 256, 0, stream>>>(aw4, WT, 3, 3, 3, 384, 384, 108, 110592);
    conv_mfma2<1, true><<<dim3(7, 4, BATCH), 256, 0, stream>>>(
        c3out, WT, ab4, c4out, 25, 19, 384, W2P, H2P * W2P, 108, 3, 25, 19, 1, 256);
    wprep_k<<<(73728 + 255) / 256, 256, 0, stream>>>(aw5, WT, 3, 3, 3, 256, 256, 72, 73728);
    conv_mfma2<1, true><<<dim3(7, 4, BATCH), 256, 0, stream>>>(
        c4out, WT, ab5, c5out, 25, 19, 256, W2P, H2P * W2P, 72, 3, H2P, W2P, 0, 256);

    // ---- tail region layout in R1 ----
    float*    P      = R1 + 2417664;
    ushort_t* PB     = (ushort_t*)(R1 + 2800640);
    ushort_t* XfPad  = (ushort_t*)(R1 + 2992128);
    float*    xc     = R1 + 3003648;

    ushort_t* WS1T = (ushort_t*)Wg;
    ushort_t* WS2T = (ushort_t*)(Wg + 65536);
    ushort_t* WCDT = (ushort_t*)(Wg + 131072);
    wprep2_k<0><<<(16384 + 255) / 256, 256, 0, stream>>>(ws1, WS1T, 1, 512, 8, 16384);
    wprep2_k<0><<<(16384 + 255) / 256, 256, 0, stream>>>(ws2, WS2T, 1, 256, 16, 16384);
    wprep2_k<1><<<(24576 + 255) / 256, 256, 0, stream>>>(wcd, WCDT, 0, 0, 24, 24576);

    zfill_k<<<(2880 + 255) / 256, 256, 0, stream>>>((float4*)XfPad, 2880);
    pool5_k<<<(BATCH * 256 * MM + 255) / 256, 256, 0, stream>>>(c5out, P, PB, XfPad);
    float* Xf2 = P;

    float* v_   = R1 + 0;
    float* xhat = R1 + 1024;
    float* Y1   = R1 + 23552;
    float* S1   = R1 + 744448;
    ushort_t* h1b = (ushort_t*)(R1 + 752640);
    float* Y2   = R1 + 1473536;
    float* S2   = R1 + 1833984;
    float* h2   = R1 + 1838080;
    float* V1   = R1 + 2198528;
    float* Vx   = R1 + 2221056;
    float* G    = R1 + 2243584;
    float* Hh   = R1 + 2266112;
    float* Sm   = R1 + 2288640;
    float* A2   = R1 + 2296832;
    float* t1   = R1 + 2305024;
    float* c1   = R1 + 2338816;
    float* t2   = R1 + 2372608;
    float* V2m  = R1 + 2395136;

    gemm_mfma<0, true, false><<<dim3(2, 4), 256, 0, stream>>>(
        XfPad, WCDT, bcd, xc, 256, MM, 24, 1, MM);
    vmax_k<<<4, 64, 0, stream>>>(xc, v_);
    xhat_k<<<(DD * MM + 255) / 256, 256, 0, stream>>>(v_, wt, bt, xhat);

    gemm_mfma<1, false, true><<<dim3(22, 8), 256, 0, stream>>>(
        PB, WS1T, nullptr, Y1, 256, TM, 8, 512, 1);
    s1_k<<<(T_EX * 512 + 255) / 256, 256, 0, stream>>>(Y1, S1);
    h1_k<<<(TM * 512 + 255) / 256, 256, 0, stream>>>(Y1, S1, bs1, h1b);
    gemm_mfma<0, false, true><<<dim3(22, 4), 256, 0, stream>>>(
        h1b, WS2T, nullptr, Y2, 512, TM, 16, 256, 1);
    s2_k<<<(T_EX * 256 + 255) / 256, 256, 0, stream>>>(Y2, S2);
    h2_k<<<(TM * 256 + 255) / 256, 256, 0, stream>>>(Y2, S2, bs2, h2);
    v1vx_k<<<(DD * MM + 255) / 256, 256, 0, stream>>>(h2, xhat, V1, Vx);

    lin88_k<<<dim3((DD * MM + 255) / 256, 2), 256, 0, stream>>>(wg, bg, wh, bh, Vx, G, Hh);
    smat_k<<<(MM * MM + 255) / 256, 256, 0, stream>>>(Hh, G, Sm);
    softmax_k<<<MM, 128, 0, stream>>>(Sm, A2);

    t1_k<<<(MM * 384 + 255) / 256, 256, 0, stream>>>(V1, wc1, t1);
    c1_k<<<(MM * 384 + 255) / 256, 256, 0, stream>>>(A2, t1, bc1, c1);
    t2_k<<<(MM * 256 + 255) / 256, 256, 0, stream>>>(c1, wc2, t2);
    v2_k<<<(MM * 256 + 255) / 256, 256, 0, stream>>>(A2, t2, bc2, V2m);

    final_k<<<1, 256, 0, stream>>>(Xf2, V2m, (float*)d_out);
}